// Round 1
// baseline (9037.509 us; speedup 1.0000x reference)
//
#include <hip/hip_runtime.h>

#define NU_ 100000
#define NI_ 50000
#define NA_ 5000
#define FEAT_ 256
#define H_ 128
#define ER_ 1000000
#define ES_ 500000
#define EH_ 250000

typedef long long i64;

__global__ __launch_bounds__(256) void fillz_kernel(float4* __restrict__ p, long n4) {
    long i = (long)blockIdx.x * 256 + threadIdx.x;
    if (i < n4) p[i] = make_float4(0.f, 0.f, 0.f, 0.f);
}

__global__ __launch_bounds__(256) void deg_kernel(const int* __restrict__ src,
                                                  const int* __restrict__ dst,
                                                  int E,
                                                  float* __restrict__ cntDst,
                                                  float* __restrict__ cntSrc) {
    int e = blockIdx.x * 256 + threadIdx.x;
    if (e >= E) return;
    atomicAdd(&cntDst[dst[e]], 1.0f);
    if (cntSrc != nullptr) atomicAdd(&cntSrc[src[e]], 1.0f);
}

// One edge handled by 32 lanes; each lane moves 4 floats (float4 gather + 4 atomic adds).
__global__ __launch_bounds__(256) void agg_kernel(const float* __restrict__ feat,
                                                  const int* __restrict__ src,
                                                  const int* __restrict__ dst,
                                                  int E,
                                                  float* __restrict__ agg) {
    long idx = (long)blockIdx.x * 256 + threadIdx.x;
    if (idx >= (long)E * 32) return;
    long e = idx >> 5;
    int c = (int)(idx & 31) * 4;
    int s = src[e], d = dst[e];
    float4 v = *(const float4*)&feat[(i64)s * H_ + c];
    float* o = &agg[(i64)d * H_ + c];
    atomicAdd(o + 0, v.x);
    atomicAdd(o + 1, v.y);
    atomicAdd(o + 2, v.z);
    atomicAdd(o + 3, v.w);
}

// Wout = Wa + Wb + Wc (128x128); bout = 0.5*(b1+b2)
__global__ __launch_bounds__(256) void combine_kernel(const float* __restrict__ Wa,
                                                      const float* __restrict__ Wb,
                                                      const float* __restrict__ Wc,
                                                      const float* __restrict__ b1,
                                                      const float* __restrict__ b2,
                                                      float* __restrict__ Wout,
                                                      float* __restrict__ bout) {
    int i = blockIdx.x * 256 + threadIdx.x;
    if (i < H_ * H_) {
        Wout[i] = Wa[i] + Wb[i] + Wc[i];
    } else if (i < H_ * H_ + H_) {
        int j = i - H_ * H_;
        bout[j] = 0.5f * (b1[j] + b2[j]);
    }
}

// C[M][128] = act( scale * ( rowscale(A1) @ W1  [+ A2 @ W2] ) + bias )
// rowscale = 1/max(cnt[row],1) if cnt != null.
// A1: M x K1 (K1 = 128 or 256), W1: K1 x 128. A2: M x 128, W2: 128 x 128 (DUAL only).
template <bool DUAL>
__global__ __launch_bounds__(256) void gemm_kernel(
    const float* __restrict__ A1, int lda1, int K1,
    const float* __restrict__ cnt,
    const float* __restrict__ W1,
    const float* __restrict__ A2,
    const float* __restrict__ W2,
    const float* __restrict__ bias,
    float scale, int do_relu,
    float* __restrict__ C, int M) {
    __shared__ float As1[128][68];
    __shared__ float As2[DUAL ? 128 : 1][DUAL ? 68 : 1];

    int t = threadIdx.x;
    int m0 = blockIdx.x * 64;
    int k4 = t & 31;   // staging: k quad
    int rb = t >> 5;   // staging: row base
    int nG = t & 31;   // compute: n group (4 cols)
    int mG = t >> 5;   // compute: m group (8 rows)

    float acc[8][4];
#pragma unroll
    for (int i = 0; i < 8; ++i)
#pragma unroll
        for (int j = 0; j < 4; ++j) acc[i][j] = 0.f;

    int ktiles = K1 >> 7;
    for (int kt = 0; kt < ktiles; ++kt) {
        // stage A1^T (rows m0..m0+63, k-tile) into LDS, row-scaled
#pragma unroll
        for (int p = 0; p < 8; ++p) {
            int r = rb + p * 8;
            int row = m0 + r;
            float4 v = make_float4(0.f, 0.f, 0.f, 0.f);
            float rs = 1.0f;
            if (row < M) {
                v = *(const float4*)&A1[(i64)row * lda1 + kt * 128 + k4 * 4];
                if (cnt != nullptr) rs = 1.0f / fmaxf(cnt[row], 1.0f);
            }
            As1[k4 * 4 + 0][r] = v.x * rs;
            As1[k4 * 4 + 1][r] = v.y * rs;
            As1[k4 * 4 + 2][r] = v.z * rs;
            As1[k4 * 4 + 3][r] = v.w * rs;
        }
        if (DUAL && kt == 0) {
#pragma unroll
            for (int p = 0; p < 8; ++p) {
                int r = rb + p * 8;
                int row = m0 + r;
                float4 v = make_float4(0.f, 0.f, 0.f, 0.f);
                if (row < M) v = *(const float4*)&A2[(i64)row * H_ + k4 * 4];
                As2[k4 * 4 + 0][r] = v.x;
                As2[k4 * 4 + 1][r] = v.y;
                As2[k4 * 4 + 2][r] = v.z;
                As2[k4 * 4 + 3][r] = v.w;
            }
        }
        __syncthreads();

        const float* w1p = &W1[(i64)(kt * 128) * H_ + nG * 4];
        if (DUAL && kt == 0) {
            const float* w2p = &W2[nG * 4];
#pragma unroll 2
            for (int k = 0; k < 128; ++k) {
                float4 w1 = *(const float4*)w1p; w1p += H_;
                float4 w2 = *(const float4*)w2p; w2p += H_;
                float a1[8], a2[8];
                *(float4*)&a1[0] = *(const float4*)&As1[k][mG * 8];
                *(float4*)&a1[4] = *(const float4*)&As1[k][mG * 8 + 4];
                *(float4*)&a2[0] = *(const float4*)&As2[k][mG * 8];
                *(float4*)&a2[4] = *(const float4*)&As2[k][mG * 8 + 4];
                float w1v[4] = {w1.x, w1.y, w1.z, w1.w};
                float w2v[4] = {w2.x, w2.y, w2.z, w2.w};
#pragma unroll
                for (int i = 0; i < 8; ++i)
#pragma unroll
                    for (int j = 0; j < 4; ++j)
                        acc[i][j] += a1[i] * w1v[j] + a2[i] * w2v[j];
            }
        } else {
#pragma unroll 2
            for (int k = 0; k < 128; ++k) {
                float4 w1 = *(const float4*)w1p; w1p += H_;
                float a1[8];
                *(float4*)&a1[0] = *(const float4*)&As1[k][mG * 8];
                *(float4*)&a1[4] = *(const float4*)&As1[k][mG * 8 + 4];
                float w1v[4] = {w1.x, w1.y, w1.z, w1.w};
#pragma unroll
                for (int i = 0; i < 8; ++i)
#pragma unroll
                    for (int j = 0; j < 4; ++j)
                        acc[i][j] += a1[i] * w1v[j];
            }
        }
        __syncthreads();
    }

    float4 bv = *(const float4*)&bias[nG * 4];
    float bvv[4] = {bv.x, bv.y, bv.z, bv.w};
#pragma unroll
    for (int i = 0; i < 8; ++i) {
        int row = m0 + mG * 8 + i;
        if (row < M) {
            float o[4];
#pragma unroll
            for (int j = 0; j < 4; ++j) {
                o[j] = scale * acc[i][j] + bvv[j];
                if (do_relu) o[j] = fmaxf(o[j], 0.f);
            }
            *(float4*)&C[(i64)row * H_ + nG * 4] = *(float4*)o;
        }
    }
}

__global__ __launch_bounds__(256) void fuse_kernel(const float* __restrict__ alpha,
                                                   const float* __restrict__ hui,
                                                   const float* __restrict__ hii,
                                                   const float* __restrict__ hia,
                                                   float* __restrict__ fused,
                                                   float* __restrict__ wout) {
    long i = (long)blockIdx.x * 256 + threadIdx.x;
    float a0 = alpha[0], a1 = alpha[1], a2 = alpha[2];
    float mx = fmaxf(a0, fmaxf(a1, a2));
    float e0 = expf(a0 - mx), e1 = expf(a1 - mx), e2 = expf(a2 - mx);
    float inv = 1.f / (e0 + e1 + e2);
    float w0 = e0 * inv, w1 = e1 * inv, w2 = e2 * inv;
    if (i == 0) { wout[0] = w0; wout[1] = w1; wout[2] = w2; }
    long n4 = (long)NI_ * H_ / 4;
    if (i < n4) {
        float4 u = ((const float4*)hui)[i];
        float4 v = ((const float4*)hii)[i];
        float4 t = ((const float4*)hia)[i];
        float4 o;
        o.x = w0 * u.x + w1 * v.x + w2 * t.x;
        o.y = w0 * u.y + w1 * v.y + w2 * t.y;
        o.z = w0 * u.z + w1 * v.z + w2 * t.z;
        o.w = w0 * u.w + w1 * v.w + w2 * t.w;
        ((float4*)fused)[i] = o;
    }
}

extern "C" void kernel_launch(void* const* d_in, const int* in_sizes, int n_in,
                              void* d_out, int out_size, void* d_ws, size_t ws_size,
                              hipStream_t stream) {
    const float* xif  = (const float*)d_in[0];
    const float* uemb = (const float*)d_in[1];
    const float* aemb = (const float*)d_in[2];
    const float* liW  = (const float*)d_in[3];
    const float* lib  = (const float*)d_in[4];
    const float* uiWl = (const float*)d_in[5];
    const float* uibl = (const float*)d_in[6];
    const float* uiWr = (const float*)d_in[7];
    const float* iiWl = (const float*)d_in[8];
    const float* iibl = (const float*)d_in[9];
    const float* iiWr = (const float*)d_in[10];
    const float* iaWl = (const float*)d_in[11];
    const float* iabl = (const float*)d_in[12];
    const float* iaWr = (const float*)d_in[13];
    const float* alpha = (const float*)d_in[14];
    const int* er = (const int*)d_in[15];
    const int* es = (const int*)d_in[16];
    const int* eh = (const int*)d_in[17];

    float* out = (float*)d_out;
    float* X      = out;                       // h_fused slot doubles as x_item scratch
    float* OUT_UI = out + (i64)NI_ * H_;
    float* OUT_II = out + (i64)2 * NI_ * H_;
    float* OUT_IA = out + (i64)3 * NI_ * H_;
    float* WOUT   = out + (i64)4 * NI_ * H_;

    float* ws = (float*)d_ws;
    i64 off = 0;
    float* HU1 = ws + off; off += (i64)NU_ * H_;   // 12.8M
    float* HI1 = ws + off; off += (i64)NI_ * H_;   // 6.4M
    float* AGG = ws + off; off += (i64)NU_ * H_;   // 12.8M
    float* HA1 = ws + off; off += (i64)NA_ * H_;   // 0.64M
    float* CNT = ws + off; off += 255000;
    float* WC  = ws + off; off += (i64)8 * 16384;
    float* BC  = ws + off; off += 8 * 128;

    float* cnt_ri = CNT;            // item deg from rates (dst)
    float* cnt_ru = CNT + 50000;    // user deg from rates (src)
    float* cnt_si = CNT + 150000;   // item deg from sim (dst)
    float* cnt_ha = CNT + 200000;   // attr deg from has (dst)
    float* cnt_hi = CNT + 205000;   // item deg from has (src)

    auto fill0 = [&](float* p, long nfloats) {
        long n4 = nfloats / 4;
        fillz_kernel<<<(int)((n4 + 255) / 256), 256, 0, stream>>>((float4*)p, n4);
    };

    // degree counts (layer-invariant)
    fill0(CNT, 255000);
    deg_kernel<<<(ER_ + 255) / 256, 256, 0, stream>>>(er, er + ER_, ER_, cnt_ri, cnt_ru);
    deg_kernel<<<(ES_ + 255) / 256, 256, 0, stream>>>(es, es + ES_, ES_, cnt_si, nullptr);
    deg_kernel<<<(EH_ + 255) / 256, 256, 0, stream>>>(eh, eh + EH_, EH_, cnt_ha, cnt_hi);

    // combined self/root weights: WC[s] = Wr[e] + Wl[s_] + Wr[s_]; BC = 0.5*(bl[e]+bl[s_])
    auto comb = [&](int slot, const float* Wl, const float* Wr, const float* bl,
                    int idx_e, int idx_s) {
        combine_kernel<<<(16512 + 255) / 256, 256, 0, stream>>>(
            Wr + (i64)idx_e * 16384, Wl + (i64)idx_s * 16384, Wr + (i64)idx_s * 16384,
            bl + (i64)idx_e * 128, bl + (i64)idx_s * 128,
            WC + (i64)slot * 16384, BC + (i64)slot * 128);
    };
    comb(0, uiWl, uiWr, uibl, 0, 3);          // UI L0 item
    comb(1, uiWl, uiWr, uibl, 1, 2);          // UI L0 user
    comb(2, uiWl, uiWr, uibl, 4 + 0, 4 + 3);  // UI L1 item
    comb(3, iiWl, iiWr, iibl, 0, 1);          // II L0
    comb(4, iiWl, iiWr, iibl, 2 + 0, 2 + 1);  // II L1
    comb(5, iaWl, iaWr, iabl, 0, 3);          // IA L0 attr
    comb(6, iaWl, iaWr, iabl, 1, 2);          // IA L0 item
    comb(7, iaWl, iaWr, iabl, 4 + 1, 4 + 2);  // IA L1 item

    // x_item = xif @ liW + lib   (no relu)
    gemm_kernel<false><<<(NI_ + 63) / 64, 256, 0, stream>>>(
        xif, FEAT_, FEAT_, nullptr, liW, nullptr, nullptr, lib, 1.0f, 0, X, NI_);

    auto agg_run = [&](const float* feat, const int* s, const int* d, int E, long ndst) {
        fill0(AGG, ndst * H_);
        long tot = (long)E * 32;
        agg_kernel<<<(int)((tot + 255) / 256), 256, 0, stream>>>(feat, s, d, E, AGG);
    };
    auto gemm2 = [&](const float* cnt, const float* W1, const float* A2, int slot,
                     float* Cout, int M) {
        gemm_kernel<true><<<(M + 63) / 64, 256, 0, stream>>>(
            AGG, H_, H_, cnt, W1, A2, WC + (i64)slot * 16384, BC + (i64)slot * 128,
            0.5f, 1, Cout, M);
    };

    // ---- UI branch ----
    // L0: o_i
    agg_run(uemb, er, er + ER_, ER_, NI_);
    gemm2(cnt_ri, uiWl + (i64)0 * 16384, X, 0, HI1, NI_);
    // L0: o_u
    agg_run(X, er + ER_, er, ER_, NU_);
    gemm2(cnt_ru, uiWl + (i64)1 * 16384, uemb, 1, HU1, NU_);
    // L1: o_i only (o_u is dead)
    agg_run(HU1, er, er + ER_, ER_, NI_);
    gemm2(cnt_ri, uiWl + (i64)(4 + 0) * 16384, HI1, 2, OUT_UI, NI_);

    // ---- II branch ----
    agg_run(X, es, es + ES_, ES_, NI_);
    gemm2(cnt_si, iiWl + (i64)0 * 16384, X, 3, HI1, NI_);
    agg_run(HI1, es, es + ES_, ES_, NI_);
    gemm2(cnt_si, iiWl + (i64)(2 + 0) * 16384, HI1, 4, OUT_II, NI_);

    // ---- IA branch ----
    // L0: o_a
    agg_run(X, eh, eh + EH_, EH_, NA_);
    gemm2(cnt_ha, iaWl + (i64)0 * 16384, aemb, 5, HA1, NA_);
    // L0: o_i
    agg_run(aemb, eh + EH_, eh, EH_, NI_);
    gemm2(cnt_hi, iaWl + (i64)1 * 16384, X, 6, HI1, NI_);
    // L1: o_i only (o_a is dead)
    agg_run(HA1, eh + EH_, eh, EH_, NI_);
    gemm2(cnt_hi, iaWl + (i64)(4 + 1) * 16384, HI1, 7, OUT_IA, NI_);

    // ---- fuse ----
    long n4 = (long)NI_ * H_ / 4;
    fuse_kernel<<<(int)((n4 + 255) / 256), 256, 0, stream>>>(
        alpha, OUT_UI, OUT_II, OUT_IA, X, WOUT);
}

// Round 2
// 1974.562 us; speedup vs baseline: 4.5770x; 4.5770x over previous
//
#include <hip/hip_runtime.h>

#define NU_ 100000
#define NI_ 50000
#define NA_ 5000
#define FEAT_ 256
#define H_ 128
#define ER_ 1000000
#define ES_ 500000
#define EH_ 250000

typedef long long i64;

__global__ __launch_bounds__(256) void fillz_kernel(float4* __restrict__ p, long n4) {
    long i = (long)blockIdx.x * 256 + threadIdx.x;
    if (i < n4) p[i] = make_float4(0.f, 0.f, 0.f, 0.f);
}

// count occurrences of keys
__global__ __launch_bounds__(256) void count_kernel(const int* __restrict__ keys, int E,
                                                    int* __restrict__ cnt) {
    int e = blockIdx.x * 256 + threadIdx.x;
    if (e >= E) return;
    atomicAdd(&cnt[keys[e]], 1);
}

// single-block exclusive-scan: off[i] = sum(cnt[0..i-1]) for i in [0,n)
__global__ __launch_bounds__(1024) void scan_kernel(const int* __restrict__ cnt, int n,
                                                    int* __restrict__ off) {
    __shared__ int sdata[1024];
    __shared__ int carry;
    int t = threadIdx.x;
    if (t == 0) carry = 0;
    __syncthreads();
    for (int base = 0; base < n; base += 1024) {
        int c = carry;
        int i = base + t;
        int v = (i < n) ? cnt[i] : 0;
        sdata[t] = v;
        __syncthreads();
#pragma unroll
        for (int s = 1; s < 1024; s <<= 1) {
            int add = (t >= s) ? sdata[t - s] : 0;
            __syncthreads();
            sdata[t] += add;
            __syncthreads();
        }
        int incl = sdata[t];
        if (i < n) off[i] = c + incl - v;
        int total = sdata[1023];
        __syncthreads();
        if (t == 0) carry = c + total;
        __syncthreads();
    }
}

// scatter edges into CSR buckets; mutates off[] so that afterwards off[i] = end of bucket i
__global__ __launch_bounds__(256) void fill_kernel(const int* __restrict__ keys,
                                                   const int* __restrict__ vals, int E,
                                                   int* __restrict__ off,
                                                   int* __restrict__ idx) {
    int e = blockIdx.x * 256 + threadIdx.x;
    if (e >= E) return;
    int pos = atomicAdd(&off[keys[e]], 1);
    idx[pos] = vals[e];
}

// gather-mean: 32 lanes per dst row, float4 per lane. off[] is the mutated
// (end-of-bucket) array: start = (row==0 ? 0 : off[row-1]), end = off[row].
__global__ __launch_bounds__(256) void gather_kernel(const float* __restrict__ feat,
                                                     const int* __restrict__ off,
                                                     const int* __restrict__ idx,
                                                     int n,
                                                     float* __restrict__ agg) {
    int row = blockIdx.x * 8 + (threadIdx.x >> 5);
    if (row >= n) return;
    int lane = (threadIdx.x & 31) * 4;
    int start = (row == 0) ? 0 : off[row - 1];
    int end = off[row];
    float4 a0 = make_float4(0.f, 0.f, 0.f, 0.f);
    float4 a1 = make_float4(0.f, 0.f, 0.f, 0.f);
    int j = start;
    for (; j + 2 <= end; j += 2) {
        int s0 = idx[j], s1 = idx[j + 1];
        float4 v0 = *(const float4*)&feat[(i64)s0 * H_ + lane];
        float4 v1 = *(const float4*)&feat[(i64)s1 * H_ + lane];
        a0.x += v0.x; a0.y += v0.y; a0.z += v0.z; a0.w += v0.w;
        a1.x += v1.x; a1.y += v1.y; a1.z += v1.z; a1.w += v1.w;
    }
    if (j < end) {
        int s0 = idx[j];
        float4 v0 = *(const float4*)&feat[(i64)s0 * H_ + lane];
        a0.x += v0.x; a0.y += v0.y; a0.z += v0.z; a0.w += v0.w;
    }
    float inv = 1.0f / fmaxf((float)(end - start), 1.0f);
    float4 o;
    o.x = (a0.x + a1.x) * inv;
    o.y = (a0.y + a1.y) * inv;
    o.z = (a0.z + a1.z) * inv;
    o.w = (a0.w + a1.w) * inv;
    *(float4*)&agg[(i64)row * H_ + lane] = o;
}

// Wout = Wa + Wb + Wc (128x128); bout = 0.5*(b1+b2)
__global__ __launch_bounds__(256) void combine_kernel(const float* __restrict__ Wa,
                                                      const float* __restrict__ Wb,
                                                      const float* __restrict__ Wc,
                                                      const float* __restrict__ b1,
                                                      const float* __restrict__ b2,
                                                      float* __restrict__ Wout,
                                                      float* __restrict__ bout) {
    int i = blockIdx.x * 256 + threadIdx.x;
    if (i < H_ * H_) {
        Wout[i] = Wa[i] + Wb[i] + Wc[i];
    } else if (i < H_ * H_ + H_) {
        int j = i - H_ * H_;
        bout[j] = 0.5f * (b1[j] + b2[j]);
    }
}

// C[M][128] = act( scale * ( A1 @ W1  [+ A2 @ W2] ) + bias )
// A1: M x K1 (K1 = 128 or 256), W1: K1 x 128. A2: M x 128, W2: 128 x 128 (DUAL only).
template <bool DUAL>
__global__ __launch_bounds__(256) void gemm_kernel(
    const float* __restrict__ A1, int lda1, int K1,
    const float* __restrict__ W1,
    const float* __restrict__ A2,
    const float* __restrict__ W2,
    const float* __restrict__ bias,
    float scale, int do_relu,
    float* __restrict__ C, int M) {
    __shared__ float As1[128][68];
    __shared__ float As2[DUAL ? 128 : 1][DUAL ? 68 : 1];

    int t = threadIdx.x;
    int m0 = blockIdx.x * 64;
    int k4 = t & 31;   // staging: k quad
    int rb = t >> 5;   // staging: row base
    int nG = t & 31;   // compute: n group (4 cols)
    int mG = t >> 5;   // compute: m group (8 rows)

    float acc[8][4];
#pragma unroll
    for (int i = 0; i < 8; ++i)
#pragma unroll
        for (int j = 0; j < 4; ++j) acc[i][j] = 0.f;

    int ktiles = K1 >> 7;
    for (int kt = 0; kt < ktiles; ++kt) {
#pragma unroll
        for (int p = 0; p < 8; ++p) {
            int r = rb + p * 8;
            int row = m0 + r;
            float4 v = make_float4(0.f, 0.f, 0.f, 0.f);
            if (row < M) v = *(const float4*)&A1[(i64)row * lda1 + kt * 128 + k4 * 4];
            As1[k4 * 4 + 0][r] = v.x;
            As1[k4 * 4 + 1][r] = v.y;
            As1[k4 * 4 + 2][r] = v.z;
            As1[k4 * 4 + 3][r] = v.w;
        }
        if (DUAL && kt == 0) {
#pragma unroll
            for (int p = 0; p < 8; ++p) {
                int r = rb + p * 8;
                int row = m0 + r;
                float4 v = make_float4(0.f, 0.f, 0.f, 0.f);
                if (row < M) v = *(const float4*)&A2[(i64)row * H_ + k4 * 4];
                As2[k4 * 4 + 0][r] = v.x;
                As2[k4 * 4 + 1][r] = v.y;
                As2[k4 * 4 + 2][r] = v.z;
                As2[k4 * 4 + 3][r] = v.w;
            }
        }
        __syncthreads();

        const float* w1p = &W1[(i64)(kt * 128) * H_ + nG * 4];
        if (DUAL && kt == 0) {
            const float* w2p = &W2[nG * 4];
#pragma unroll 2
            for (int k = 0; k < 128; ++k) {
                float4 w1 = *(const float4*)w1p; w1p += H_;
                float4 w2 = *(const float4*)w2p; w2p += H_;
                float a1[8], a2[8];
                *(float4*)&a1[0] = *(const float4*)&As1[k][mG * 8];
                *(float4*)&a1[4] = *(const float4*)&As1[k][mG * 8 + 4];
                *(float4*)&a2[0] = *(const float4*)&As2[k][mG * 8];
                *(float4*)&a2[4] = *(const float4*)&As2[k][mG * 8 + 4];
                float w1v[4] = {w1.x, w1.y, w1.z, w1.w};
                float w2v[4] = {w2.x, w2.y, w2.z, w2.w};
#pragma unroll
                for (int i = 0; i < 8; ++i)
#pragma unroll
                    for (int j = 0; j < 4; ++j)
                        acc[i][j] += a1[i] * w1v[j] + a2[i] * w2v[j];
            }
        } else {
#pragma unroll 2
            for (int k = 0; k < 128; ++k) {
                float4 w1 = *(const float4*)w1p; w1p += H_;
                float a1[8];
                *(float4*)&a1[0] = *(const float4*)&As1[k][mG * 8];
                *(float4*)&a1[4] = *(const float4*)&As1[k][mG * 8 + 4];
                float w1v[4] = {w1.x, w1.y, w1.z, w1.w};
#pragma unroll
                for (int i = 0; i < 8; ++i)
#pragma unroll
                    for (int j = 0; j < 4; ++j)
                        acc[i][j] += a1[i] * w1v[j];
            }
        }
        __syncthreads();
    }

    float4 bv = *(const float4*)&bias[nG * 4];
    float bvv[4] = {bv.x, bv.y, bv.z, bv.w};
#pragma unroll
    for (int i = 0; i < 8; ++i) {
        int row = m0 + mG * 8 + i;
        if (row < M) {
            float o[4];
#pragma unroll
            for (int j = 0; j < 4; ++j) {
                o[j] = scale * acc[i][j] + bvv[j];
                if (do_relu) o[j] = fmaxf(o[j], 0.f);
            }
            *(float4*)&C[(i64)row * H_ + nG * 4] = *(float4*)o;
        }
    }
}

__global__ __launch_bounds__(256) void fuse_kernel(const float* __restrict__ alpha,
                                                   const float* __restrict__ hui,
                                                   const float* __restrict__ hii,
                                                   const float* __restrict__ hia,
                                                   float* __restrict__ fused,
                                                   float* __restrict__ wout) {
    long i = (long)blockIdx.x * 256 + threadIdx.x;
    float a0 = alpha[0], a1 = alpha[1], a2 = alpha[2];
    float mx = fmaxf(a0, fmaxf(a1, a2));
    float e0 = expf(a0 - mx), e1 = expf(a1 - mx), e2 = expf(a2 - mx);
    float inv = 1.f / (e0 + e1 + e2);
    float w0 = e0 * inv, w1 = e1 * inv, w2 = e2 * inv;
    if (i == 0) { wout[0] = w0; wout[1] = w1; wout[2] = w2; }
    long n4 = (long)NI_ * H_ / 4;
    if (i < n4) {
        float4 u = ((const float4*)hui)[i];
        float4 v = ((const float4*)hii)[i];
        float4 t = ((const float4*)hia)[i];
        float4 o;
        o.x = w0 * u.x + w1 * v.x + w2 * t.x;
        o.y = w0 * u.y + w1 * v.y + w2 * t.y;
        o.z = w0 * u.z + w1 * v.z + w2 * t.z;
        o.w = w0 * u.w + w1 * v.w + w2 * t.w;
        ((float4*)fused)[i] = o;
    }
}

extern "C" void kernel_launch(void* const* d_in, const int* in_sizes, int n_in,
                              void* d_out, int out_size, void* d_ws, size_t ws_size,
                              hipStream_t stream) {
    const float* xif  = (const float*)d_in[0];
    const float* uemb = (const float*)d_in[1];
    const float* aemb = (const float*)d_in[2];
    const float* liW  = (const float*)d_in[3];
    const float* lib  = (const float*)d_in[4];
    const float* uiWl = (const float*)d_in[5];
    const float* uibl = (const float*)d_in[6];
    const float* uiWr = (const float*)d_in[7];
    const float* iiWl = (const float*)d_in[8];
    const float* iibl = (const float*)d_in[9];
    const float* iiWr = (const float*)d_in[10];
    const float* iaWl = (const float*)d_in[11];
    const float* iabl = (const float*)d_in[12];
    const float* iaWr = (const float*)d_in[13];
    const float* alpha = (const float*)d_in[14];
    const int* er = (const int*)d_in[15];
    const int* es = (const int*)d_in[16];
    const int* eh = (const int*)d_in[17];

    float* out = (float*)d_out;
    float* X      = out;                       // h_fused slot doubles as x_item scratch
    float* OUT_UI = out + (i64)NI_ * H_;
    float* OUT_II = out + (i64)2 * NI_ * H_;
    float* OUT_IA = out + (i64)3 * NI_ * H_;
    float* WOUT   = out + (i64)4 * NI_ * H_;

    float* ws = (float*)d_ws;
    i64 off = 0;
    float* HU1 = ws + off; off += (i64)NU_ * H_;   // 12.8M
    float* HI1 = ws + off; off += (i64)NI_ * H_;   // 6.4M
    float* AGG = ws + off; off += (i64)NU_ * H_;   // 12.8M
    float* HA1 = ws + off; off += (i64)NA_ * H_;   // 0.64M
    float* WC  = ws + off; off += (i64)8 * 16384;
    float* BC  = ws + off; off += 8 * 128;

    int* ip = (int*)(ws + off);
    i64 io = 0;
    int* off_ri = ip + io; io += NI_;
    int* off_ru = ip + io; io += NU_;
    int* off_si = ip + io; io += NI_;
    int* off_ha = ip + io; io += NA_;
    int* off_hi = ip + io; io += NI_;
    int* idx_ri = ip + io; io += ER_;
    int* idx_ru = ip + io; io += ER_;
    int* idx_si = ip + io; io += ES_;
    int* idx_ha = ip + io; io += EH_;
    int* idx_hi = ip + io; io += EH_;
    int* CNTI   = ip + io; io += NU_;  // scratch counts (max over node types)

    auto fill0i = [&](int* p, long nints) {
        long n4 = nints / 4;
        fillz_kernel<<<(int)((n4 + 255) / 256), 256, 0, stream>>>((float4*)p, n4);
    };

    // CSR build: count -> scan -> scatter-fill (off becomes end-of-bucket)
    auto build_csr = [&](const int* keys, const int* vals, int E, int n,
                         int* offx, int* idxx) {
        fill0i(CNTI, n);
        count_kernel<<<(E + 255) / 256, 256, 0, stream>>>(keys, E, CNTI);
        scan_kernel<<<1, 1024, 0, stream>>>(CNTI, n, offx);
        fill_kernel<<<(E + 255) / 256, 256, 0, stream>>>(keys, vals, E, offx, idxx);
    };

    build_csr(er + ER_, er,       ER_, NI_, off_ri, idx_ri);  // rates: dst item
    build_csr(er,       er + ER_, ER_, NU_, off_ru, idx_ru);  // rates: dst user
    build_csr(es + ES_, es,       ES_, NI_, off_si, idx_si);  // sim:   dst item
    build_csr(eh + EH_, eh,       EH_, NA_, off_ha, idx_ha);  // has:   dst attr
    build_csr(eh,       eh + EH_, EH_, NI_, off_hi, idx_hi);  // has:   dst item

    // combined self/root weights: WC[s] = Wr[e] + Wl[s_] + Wr[s_]; BC = 0.5*(bl[e]+bl[s_])
    auto comb = [&](int slot, const float* Wl, const float* Wr, const float* bl,
                    int idx_e, int idx_s) {
        combine_kernel<<<(16512 + 255) / 256, 256, 0, stream>>>(
            Wr + (i64)idx_e * 16384, Wl + (i64)idx_s * 16384, Wr + (i64)idx_s * 16384,
            bl + (i64)idx_e * 128, bl + (i64)idx_s * 128,
            WC + (i64)slot * 16384, BC + (i64)slot * 128);
    };
    comb(0, uiWl, uiWr, uibl, 0, 3);          // UI L0 item
    comb(1, uiWl, uiWr, uibl, 1, 2);          // UI L0 user
    comb(2, uiWl, uiWr, uibl, 4 + 0, 4 + 3);  // UI L1 item
    comb(3, iiWl, iiWr, iibl, 0, 1);          // II L0
    comb(4, iiWl, iiWr, iibl, 2 + 0, 2 + 1);  // II L1
    comb(5, iaWl, iaWr, iabl, 0, 3);          // IA L0 attr
    comb(6, iaWl, iaWr, iabl, 1, 2);          // IA L0 item
    comb(7, iaWl, iaWr, iabl, 4 + 1, 4 + 2);  // IA L1 item

    // x_item = xif @ liW + lib   (no relu)
    gemm_kernel<false><<<(NI_ + 63) / 64, 256, 0, stream>>>(
        xif, FEAT_, FEAT_, liW, nullptr, nullptr, lib, 1.0f, 0, X, NI_);

    auto agg_run = [&](const float* feat, const int* offx, const int* idxx, int ndst) {
        gather_kernel<<<(ndst + 7) / 8, 256, 0, stream>>>(feat, offx, idxx, ndst, AGG);
    };
    auto gemm2 = [&](const float* W1, const float* A2, int slot, float* Cout, int M) {
        gemm_kernel<true><<<(M + 63) / 64, 256, 0, stream>>>(
            AGG, H_, H_, W1, A2, WC + (i64)slot * 16384, BC + (i64)slot * 128,
            0.5f, 1, Cout, M);
    };

    // ---- UI branch ----
    agg_run(uemb, off_ri, idx_ri, NI_);
    gemm2(uiWl + (i64)0 * 16384, X, 0, HI1, NI_);
    agg_run(X, off_ru, idx_ru, NU_);
    gemm2(uiWl + (i64)1 * 16384, uemb, 1, HU1, NU_);
    agg_run(HU1, off_ri, idx_ri, NI_);              // L1 o_i only (o_u dead)
    gemm2(uiWl + (i64)(4 + 0) * 16384, HI1, 2, OUT_UI, NI_);

    // ---- II branch ----
    agg_run(X, off_si, idx_si, NI_);
    gemm2(iiWl + (i64)0 * 16384, X, 3, HI1, NI_);
    agg_run(HI1, off_si, idx_si, NI_);
    gemm2(iiWl + (i64)(2 + 0) * 16384, HI1, 4, OUT_II, NI_);

    // ---- IA branch ----
    agg_run(X, off_ha, idx_ha, NA_);
    gemm2(iaWl + (i64)0 * 16384, aemb, 5, HA1, NA_);
    agg_run(aemb, off_hi, idx_hi, NI_);
    gemm2(iaWl + (i64)1 * 16384, X, 6, HI1, NI_);
    agg_run(HA1, off_hi, idx_hi, NI_);              // L1 o_i only (o_a dead)
    gemm2(iaWl + (i64)(4 + 1) * 16384, HI1, 7, OUT_IA, NI_);

    // ---- fuse ----
    long n4 = (long)NI_ * H_ / 4;
    fuse_kernel<<<(int)((n4 + 255) / 256), 256, 0, stream>>>(
        alpha, OUT_UI, OUT_II, OUT_IA, X, WOUT);
}

// Round 3
// 1532.150 us; speedup vs baseline: 5.8986x; 1.2888x over previous
//
#include <hip/hip_runtime.h>

#define NU_ 100000
#define NI_ 50000
#define NA_ 5000
#define FEAT_ 256
#define H_ 128
#define ER_ 1000000
#define ES_ 500000
#define EH_ 250000

typedef long long i64;

__global__ __launch_bounds__(256) void fillz_kernel(float4* __restrict__ p, long n4) {
    long i = (long)blockIdx.x * 256 + threadIdx.x;
    if (i < n4) p[i] = make_float4(0.f, 0.f, 0.f, 0.f);
}

// count occurrences of keys
__global__ __launch_bounds__(256) void count_kernel(const int* __restrict__ keys, int E,
                                                    int* __restrict__ cnt) {
    int e = blockIdx.x * 256 + threadIdx.x;
    if (e >= E) return;
    atomicAdd(&cnt[keys[e]], 1);
}

// ---- 3-phase device-wide exclusive scan over cnt[0..n) ----
// phase 1: per-1024-chunk totals
__global__ __launch_bounds__(256) void bsum_kernel(const int* __restrict__ cnt, int n,
                                                   int* __restrict__ bsum) {
    int b = blockIdx.x, t = threadIdx.x;
    long i0 = (long)b * 1024 + t * 4;
    int s = 0;
    if (i0 + 4 <= n) {
        int4 v = *(const int4*)&cnt[i0];
        s = v.x + v.y + v.z + v.w;
    } else {
#pragma unroll
        for (int k = 0; k < 4; ++k)
            if (i0 + k < n) s += cnt[i0 + k];
    }
#pragma unroll
    for (int d = 32; d; d >>= 1) s += __shfl_down(s, d);
    __shared__ int ws[4];
    if ((t & 63) == 0) ws[t >> 6] = s;
    __syncthreads();
    if (t == 0) bsum[b] = ws[0] + ws[1] + ws[2] + ws[3];
}

// phase 2: single small block scans chunk totals (nb <= 128) -> exclusive
__global__ __launch_bounds__(128) void scan_top_kernel(int* __restrict__ bsum, int nb) {
    int t = threadIdx.x;
    int v = (t < nb) ? bsum[t] : 0;
    int incl = v;
    int lane = t & 63;
#pragma unroll
    for (int d = 1; d < 64; d <<= 1) {
        int u = __shfl_up(incl, d);
        if (lane >= d) incl += u;
    }
    __shared__ int w0;
    if (t == 63) w0 = incl;
    __syncthreads();
    int ex = incl - v + ((t >= 64) ? w0 : 0);
    if (t < nb) bsum[t] = ex;
}

// phase 3: per-chunk exclusive scan + chunk offset
__global__ __launch_bounds__(256) void scan_block_kernel(const int* __restrict__ cnt, int n,
                                                         const int* __restrict__ bexcl,
                                                         int* __restrict__ off) {
    int b = blockIdx.x, t = threadIdx.x;
    long i0 = (long)b * 1024 + t * 4;
    int e0 = 0, e1 = 0, e2 = 0, e3 = 0;
    if (i0 + 4 <= n) {
        int4 v = *(const int4*)&cnt[i0];
        e0 = v.x; e1 = v.y; e2 = v.z; e3 = v.w;
    } else {
        if (i0 < n) e0 = cnt[i0];
        if (i0 + 1 < n) e1 = cnt[i0 + 1];
        if (i0 + 2 < n) e2 = cnt[i0 + 2];
        if (i0 + 3 < n) e3 = cnt[i0 + 3];
    }
    int tsum = e0 + e1 + e2 + e3;
    int incl = tsum;
    int lane = t & 63;
#pragma unroll
    for (int d = 1; d < 64; d <<= 1) {
        int u = __shfl_up(incl, d);
        if (lane >= d) incl += u;
    }
    __shared__ int wt[4];
    if (lane == 63) wt[t >> 6] = incl;
    __syncthreads();
    int w = t >> 6, wo = 0;
    for (int i = 0; i < w; ++i) wo += wt[i];
    int ex = incl - tsum + wo + bexcl[b];
    if (i0 < n) off[i0] = ex;
    if (i0 + 1 < n) off[i0 + 1] = ex + e0;
    if (i0 + 2 < n) off[i0 + 2] = ex + e0 + e1;
    if (i0 + 3 < n) off[i0 + 3] = ex + e0 + e1 + e2;
}

// scatter edges into CSR buckets; mutates off[] so that afterwards off[i] = end of bucket i
__global__ __launch_bounds__(256) void fill_kernel(const int* __restrict__ keys,
                                                   const int* __restrict__ vals, int E,
                                                   int* __restrict__ off,
                                                   int* __restrict__ idx) {
    int e = blockIdx.x * 256 + threadIdx.x;
    if (e >= E) return;
    int pos = atomicAdd(&off[keys[e]], 1);
    idx[pos] = vals[e];
}

// gather-mean: 32 lanes per dst row, float4 per lane. off[] is the mutated
// (end-of-bucket) array: start = (row==0 ? 0 : off[row-1]), end = off[row].
__global__ __launch_bounds__(256) void gather_kernel(const float* __restrict__ feat,
                                                     const int* __restrict__ off,
                                                     const int* __restrict__ idx,
                                                     int n,
                                                     float* __restrict__ agg) {
    int row = blockIdx.x * 8 + (threadIdx.x >> 5);
    if (row >= n) return;
    int lane = (threadIdx.x & 31) * 4;
    int start = (row == 0) ? 0 : off[row - 1];
    int end = off[row];
    float4 a0 = make_float4(0.f, 0.f, 0.f, 0.f);
    float4 a1 = make_float4(0.f, 0.f, 0.f, 0.f);
    int j = start;
    for (; j + 2 <= end; j += 2) {
        int s0 = idx[j], s1 = idx[j + 1];
        float4 v0 = *(const float4*)&feat[(i64)s0 * H_ + lane];
        float4 v1 = *(const float4*)&feat[(i64)s1 * H_ + lane];
        a0.x += v0.x; a0.y += v0.y; a0.z += v0.z; a0.w += v0.w;
        a1.x += v1.x; a1.y += v1.y; a1.z += v1.z; a1.w += v1.w;
    }
    if (j < end) {
        int s0 = idx[j];
        float4 v0 = *(const float4*)&feat[(i64)s0 * H_ + lane];
        a0.x += v0.x; a0.y += v0.y; a0.z += v0.z; a0.w += v0.w;
    }
    float inv = 1.0f / fmaxf((float)(end - start), 1.0f);
    float4 o;
    o.x = (a0.x + a1.x) * inv;
    o.y = (a0.y + a1.y) * inv;
    o.z = (a0.z + a1.z) * inv;
    o.w = (a0.w + a1.w) * inv;
    *(float4*)&agg[(i64)row * H_ + lane] = o;
}

// Wout = Wa + Wb + Wc (128x128); bout = 0.5*(b1+b2)
__global__ __launch_bounds__(256) void combine_kernel(const float* __restrict__ Wa,
                                                      const float* __restrict__ Wb,
                                                      const float* __restrict__ Wc,
                                                      const float* __restrict__ b1,
                                                      const float* __restrict__ b2,
                                                      float* __restrict__ Wout,
                                                      float* __restrict__ bout) {
    int i = blockIdx.x * 256 + threadIdx.x;
    if (i < H_ * H_) {
        Wout[i] = Wa[i] + Wb[i] + Wc[i];
    } else if (i < H_ * H_ + H_) {
        int j = i - H_ * H_;
        bout[j] = 0.5f * (b1[j] + b2[j]);
    }
}

// C[M][128] = act( scale * ( A1 @ W1  [+ A2 @ W2] ) + bias )
// A1: M x K1 (K1 = 128 or 256), W1: K1 x 128. A2: M x 128, W2: 128 x 128 (DUAL only).
template <bool DUAL>
__global__ __launch_bounds__(256) void gemm_kernel(
    const float* __restrict__ A1, int lda1, int K1,
    const float* __restrict__ W1,
    const float* __restrict__ A2,
    const float* __restrict__ W2,
    const float* __restrict__ bias,
    float scale, int do_relu,
    float* __restrict__ C, int M) {
    __shared__ float As1[128][68];
    __shared__ float As2[DUAL ? 128 : 1][DUAL ? 68 : 1];

    int t = threadIdx.x;
    int m0 = blockIdx.x * 64;
    int k4 = t & 31;   // staging: k quad
    int rb = t >> 5;   // staging: row base
    int nG = t & 31;   // compute: n group (4 cols)
    int mG = t >> 5;   // compute: m group (8 rows)

    float acc[8][4];
#pragma unroll
    for (int i = 0; i < 8; ++i)
#pragma unroll
        for (int j = 0; j < 4; ++j) acc[i][j] = 0.f;

    int ktiles = K1 >> 7;
    for (int kt = 0; kt < ktiles; ++kt) {
#pragma unroll
        for (int p = 0; p < 8; ++p) {
            int r = rb + p * 8;
            int row = m0 + r;
            float4 v = make_float4(0.f, 0.f, 0.f, 0.f);
            if (row < M) v = *(const float4*)&A1[(i64)row * lda1 + kt * 128 + k4 * 4];
            As1[k4 * 4 + 0][r] = v.x;
            As1[k4 * 4 + 1][r] = v.y;
            As1[k4 * 4 + 2][r] = v.z;
            As1[k4 * 4 + 3][r] = v.w;
        }
        if (DUAL && kt == 0) {
#pragma unroll
            for (int p = 0; p < 8; ++p) {
                int r = rb + p * 8;
                int row = m0 + r;
                float4 v = make_float4(0.f, 0.f, 0.f, 0.f);
                if (row < M) v = *(const float4*)&A2[(i64)row * H_ + k4 * 4];
                As2[k4 * 4 + 0][r] = v.x;
                As2[k4 * 4 + 1][r] = v.y;
                As2[k4 * 4 + 2][r] = v.z;
                As2[k4 * 4 + 3][r] = v.w;
            }
        }
        __syncthreads();

        const float* w1p = &W1[(i64)(kt * 128) * H_ + nG * 4];
        if (DUAL && kt == 0) {
            const float* w2p = &W2[nG * 4];
#pragma unroll 2
            for (int k = 0; k < 128; ++k) {
                float4 w1 = *(const float4*)w1p; w1p += H_;
                float4 w2 = *(const float4*)w2p; w2p += H_;
                float a1[8], a2[8];
                *(float4*)&a1[0] = *(const float4*)&As1[k][mG * 8];
                *(float4*)&a1[4] = *(const float4*)&As1[k][mG * 8 + 4];
                *(float4*)&a2[0] = *(const float4*)&As2[k][mG * 8];
                *(float4*)&a2[4] = *(const float4*)&As2[k][mG * 8 + 4];
                float w1v[4] = {w1.x, w1.y, w1.z, w1.w};
                float w2v[4] = {w2.x, w2.y, w2.z, w2.w};
#pragma unroll
                for (int i = 0; i < 8; ++i)
#pragma unroll
                    for (int j = 0; j < 4; ++j)
                        acc[i][j] += a1[i] * w1v[j] + a2[i] * w2v[j];
            }
        } else {
#pragma unroll 2
            for (int k = 0; k < 128; ++k) {
                float4 w1 = *(const float4*)w1p; w1p += H_;
                float a1[8];
                *(float4*)&a1[0] = *(const float4*)&As1[k][mG * 8];
                *(float4*)&a1[4] = *(const float4*)&As1[k][mG * 8 + 4];
                float w1v[4] = {w1.x, w1.y, w1.z, w1.w};
#pragma unroll
                for (int i = 0; i < 8; ++i)
#pragma unroll
                    for (int j = 0; j < 4; ++j)
                        acc[i][j] += a1[i] * w1v[j];
            }
        }
        __syncthreads();
    }

    float4 bv = *(const float4*)&bias[nG * 4];
    float bvv[4] = {bv.x, bv.y, bv.z, bv.w};
#pragma unroll
    for (int i = 0; i < 8; ++i) {
        int row = m0 + mG * 8 + i;
        if (row < M) {
            float o[4];
#pragma unroll
            for (int j = 0; j < 4; ++j) {
                o[j] = scale * acc[i][j] + bvv[j];
                if (do_relu) o[j] = fmaxf(o[j], 0.f);
            }
            *(float4*)&C[(i64)row * H_ + nG * 4] = *(float4*)o;
        }
    }
}

__global__ __launch_bounds__(256) void fuse_kernel(const float* __restrict__ alpha,
                                                   const float* __restrict__ hui,
                                                   const float* __restrict__ hii,
                                                   const float* __restrict__ hia,
                                                   float* __restrict__ fused,
                                                   float* __restrict__ wout) {
    long i = (long)blockIdx.x * 256 + threadIdx.x;
    float a0 = alpha[0], a1 = alpha[1], a2 = alpha[2];
    float mx = fmaxf(a0, fmaxf(a1, a2));
    float e0 = expf(a0 - mx), e1 = expf(a1 - mx), e2 = expf(a2 - mx);
    float inv = 1.f / (e0 + e1 + e2);
    float w0 = e0 * inv, w1 = e1 * inv, w2 = e2 * inv;
    if (i == 0) { wout[0] = w0; wout[1] = w1; wout[2] = w2; }
    long n4 = (long)NI_ * H_ / 4;
    if (i < n4) {
        float4 u = ((const float4*)hui)[i];
        float4 v = ((const float4*)hii)[i];
        float4 t = ((const float4*)hia)[i];
        float4 o;
        o.x = w0 * u.x + w1 * v.x + w2 * t.x;
        o.y = w0 * u.y + w1 * v.y + w2 * t.y;
        o.z = w0 * u.z + w1 * v.z + w2 * t.z;
        o.w = w0 * u.w + w1 * v.w + w2 * t.w;
        ((float4*)fused)[i] = o;
    }
}

extern "C" void kernel_launch(void* const* d_in, const int* in_sizes, int n_in,
                              void* d_out, int out_size, void* d_ws, size_t ws_size,
                              hipStream_t stream) {
    const float* xif  = (const float*)d_in[0];
    const float* uemb = (const float*)d_in[1];
    const float* aemb = (const float*)d_in[2];
    const float* liW  = (const float*)d_in[3];
    const float* lib  = (const float*)d_in[4];
    const float* uiWl = (const float*)d_in[5];
    const float* uibl = (const float*)d_in[6];
    const float* uiWr = (const float*)d_in[7];
    const float* iiWl = (const float*)d_in[8];
    const float* iibl = (const float*)d_in[9];
    const float* iiWr = (const float*)d_in[10];
    const float* iaWl = (const float*)d_in[11];
    const float* iabl = (const float*)d_in[12];
    const float* iaWr = (const float*)d_in[13];
    const float* alpha = (const float*)d_in[14];
    const int* er = (const int*)d_in[15];
    const int* es = (const int*)d_in[16];
    const int* eh = (const int*)d_in[17];

    float* out = (float*)d_out;
    float* X      = out;                       // h_fused slot doubles as x_item scratch
    float* OUT_UI = out + (i64)NI_ * H_;
    float* OUT_II = out + (i64)2 * NI_ * H_;
    float* OUT_IA = out + (i64)3 * NI_ * H_;
    float* WOUT   = out + (i64)4 * NI_ * H_;

    float* ws = (float*)d_ws;
    i64 off = 0;
    float* HU1 = ws + off; off += (i64)NU_ * H_;   // 12.8M
    float* HI1 = ws + off; off += (i64)NI_ * H_;   // 6.4M
    float* AGG = ws + off; off += (i64)NU_ * H_;   // 12.8M
    float* HA1 = ws + off; off += (i64)NA_ * H_;   // 0.64M
    float* WC  = ws + off; off += (i64)8 * 16384;
    float* BC  = ws + off; off += 8 * 128;

    int* ip = (int*)(ws + off);
    i64 io = 0;
    int* off_ri = ip + io; io += NI_;
    int* off_ru = ip + io; io += NU_;
    int* off_si = ip + io; io += NI_;
    int* off_ha = ip + io; io += NA_;
    int* off_hi = ip + io; io += NI_;
    int* idx_ri = ip + io; io += ER_;
    int* idx_ru = ip + io; io += ER_;
    int* idx_si = ip + io; io += ES_;
    int* idx_ha = ip + io; io += EH_;
    int* idx_hi = ip + io; io += EH_;
    int* CNTI   = ip + io; io += NU_;  // scratch counts (max over node types)
    int* BSUM   = ip + io; io += 128;  // chunk totals for device-wide scan

    auto fill0i = [&](int* p, long nints) {
        long n4 = nints / 4;
        fillz_kernel<<<(int)((n4 + 255) / 256), 256, 0, stream>>>((float4*)p, n4);
    };

    // CSR build: count -> 3-phase scan -> scatter-fill (off becomes end-of-bucket)
    auto build_csr = [&](const int* keys, const int* vals, int E, int n,
                         int* offx, int* idxx) {
        int nb = (n + 1023) / 1024;
        fill0i(CNTI, n);
        count_kernel<<<(E + 255) / 256, 256, 0, stream>>>(keys, E, CNTI);
        bsum_kernel<<<nb, 256, 0, stream>>>(CNTI, n, BSUM);
        scan_top_kernel<<<1, 128, 0, stream>>>(BSUM, nb);
        scan_block_kernel<<<nb, 256, 0, stream>>>(CNTI, n, BSUM, offx);
        fill_kernel<<<(E + 255) / 256, 256, 0, stream>>>(keys, vals, E, offx, idxx);
    };

    build_csr(er + ER_, er,       ER_, NI_, off_ri, idx_ri);  // rates: dst item
    build_csr(er,       er + ER_, ER_, NU_, off_ru, idx_ru);  // rates: dst user
    build_csr(es + ES_, es,       ES_, NI_, off_si, idx_si);  // sim:   dst item
    build_csr(eh + EH_, eh,       EH_, NA_, off_ha, idx_ha);  // has:   dst attr
    build_csr(eh,       eh + EH_, EH_, NI_, off_hi, idx_hi);  // has:   dst item

    // combined self/root weights: WC[s] = Wr[e] + Wl[s_] + Wr[s_]; BC = 0.5*(bl[e]+bl[s_])
    auto comb = [&](int slot, const float* Wl, const float* Wr, const float* bl,
                    int idx_e, int idx_s) {
        combine_kernel<<<(16512 + 255) / 256, 256, 0, stream>>>(
            Wr + (i64)idx_e * 16384, Wl + (i64)idx_s * 16384, Wr + (i64)idx_s * 16384,
            bl + (i64)idx_e * 128, bl + (i64)idx_s * 128,
            WC + (i64)slot * 16384, BC + (i64)slot * 128);
    };
    comb(0, uiWl, uiWr, uibl, 0, 3);          // UI L0 item
    comb(1, uiWl, uiWr, uibl, 1, 2);          // UI L0 user
    comb(2, uiWl, uiWr, uibl, 4 + 0, 4 + 3);  // UI L1 item
    comb(3, iiWl, iiWr, iibl, 0, 1);          // II L0
    comb(4, iiWl, iiWr, iibl, 2 + 0, 2 + 1);  // II L1
    comb(5, iaWl, iaWr, iabl, 0, 3);          // IA L0 attr
    comb(6, iaWl, iaWr, iabl, 1, 2);          // IA L0 item
    comb(7, iaWl, iaWr, iabl, 4 + 1, 4 + 2);  // IA L1 item

    // x_item = xif @ liW + lib   (no relu)
    gemm_kernel<false><<<(NI_ + 63) / 64, 256, 0, stream>>>(
        xif, FEAT_, FEAT_, liW, nullptr, nullptr, lib, 1.0f, 0, X, NI_);

    auto agg_run = [&](const float* feat, const int* offx, const int* idxx, int ndst) {
        gather_kernel<<<(ndst + 7) / 8, 256, 0, stream>>>(feat, offx, idxx, ndst, AGG);
    };
    auto gemm2 = [&](const float* W1, const float* A2, int slot, float* Cout, int M) {
        gemm_kernel<true><<<(M + 63) / 64, 256, 0, stream>>>(
            AGG, H_, H_, W1, A2, WC + (i64)slot * 16384, BC + (i64)slot * 128,
            0.5f, 1, Cout, M);
    };

    // ---- UI branch ----
    agg_run(uemb, off_ri, idx_ri, NI_);
    gemm2(uiWl + (i64)0 * 16384, X, 0, HI1, NI_);
    agg_run(X, off_ru, idx_ru, NU_);
    gemm2(uiWl + (i64)1 * 16384, uemb, 1, HU1, NU_);
    agg_run(HU1, off_ri, idx_ri, NI_);              // L1 o_i only (o_u dead)
    gemm2(uiWl + (i64)(4 + 0) * 16384, HI1, 2, OUT_UI, NI_);

    // ---- II branch ----
    agg_run(X, off_si, idx_si, NI_);
    gemm2(iiWl + (i64)0 * 16384, X, 3, HI1, NI_);
    agg_run(HI1, off_si, idx_si, NI_);
    gemm2(iiWl + (i64)(2 + 0) * 16384, HI1, 4, OUT_II, NI_);

    // ---- IA branch ----
    agg_run(X, off_ha, idx_ha, NA_);
    gemm2(iaWl + (i64)0 * 16384, aemb, 5, HA1, NA_);
    agg_run(aemb, off_hi, idx_hi, NI_);
    gemm2(iaWl + (i64)1 * 16384, X, 6, HI1, NI_);
    agg_run(HA1, off_hi, idx_hi, NI_);              // L1 o_i only (o_a dead)
    gemm2(iaWl + (i64)(4 + 1) * 16384, HI1, 7, OUT_IA, NI_);

    // ---- fuse ----
    long n4 = (long)NI_ * H_ / 4;
    fuse_kernel<<<(int)((n4 + 255) / 256), 256, 0, stream>>>(
        alpha, OUT_UI, OUT_II, OUT_IA, X, WOUT);
}

// Round 4
// 1209.024 us; speedup vs baseline: 7.4750x; 1.2673x over previous
//
#include <hip/hip_runtime.h>

#define NU_ 100000
#define NI_ 50000
#define NA_ 5000
#define FEAT_ 256
#define H_ 128
#define ER_ 1000000
#define ES_ 500000
#define EH_ 250000

typedef long long i64;
typedef unsigned short u16;
typedef unsigned int u32;
typedef __attribute__((ext_vector_type(8))) short bf16x8;
typedef __attribute__((ext_vector_type(4))) float f32x4;

__global__ __launch_bounds__(256) void fillz_kernel(float4* __restrict__ p, long n4) {
    long i = (long)blockIdx.x * 256 + threadIdx.x;
    if (i < n4) p[i] = make_float4(0.f, 0.f, 0.f, 0.f);
}

// count occurrences of keys
__global__ __launch_bounds__(256) void count_kernel(const int* __restrict__ keys, int E,
                                                    int* __restrict__ cnt) {
    int e = blockIdx.x * 256 + threadIdx.x;
    if (e >= E) return;
    atomicAdd(&cnt[keys[e]], 1);
}

// ---- 3-phase device-wide exclusive scan over cnt[0..n) ----
__global__ __launch_bounds__(256) void bsum_kernel(const int* __restrict__ cnt, int n,
                                                   int* __restrict__ bsum) {
    int b = blockIdx.x, t = threadIdx.x;
    long i0 = (long)b * 1024 + t * 4;
    int s = 0;
    if (i0 + 4 <= n) {
        int4 v = *(const int4*)&cnt[i0];
        s = v.x + v.y + v.z + v.w;
    } else {
#pragma unroll
        for (int k = 0; k < 4; ++k)
            if (i0 + k < n) s += cnt[i0 + k];
    }
#pragma unroll
    for (int d = 32; d; d >>= 1) s += __shfl_down(s, d);
    __shared__ int ws[4];
    if ((t & 63) == 0) ws[t >> 6] = s;
    __syncthreads();
    if (t == 0) bsum[b] = ws[0] + ws[1] + ws[2] + ws[3];
}

__global__ __launch_bounds__(128) void scan_top_kernel(int* __restrict__ bsum, int nb) {
    int t = threadIdx.x;
    int v = (t < nb) ? bsum[t] : 0;
    int incl = v;
    int lane = t & 63;
#pragma unroll
    for (int d = 1; d < 64; d <<= 1) {
        int u = __shfl_up(incl, d);
        if (lane >= d) incl += u;
    }
    __shared__ int w0;
    if (t == 63) w0 = incl;
    __syncthreads();
    int ex = incl - v + ((t >= 64) ? w0 : 0);
    if (t < nb) bsum[t] = ex;
}

__global__ __launch_bounds__(256) void scan_block_kernel(const int* __restrict__ cnt, int n,
                                                         const int* __restrict__ bexcl,
                                                         int* __restrict__ off) {
    int b = blockIdx.x, t = threadIdx.x;
    long i0 = (long)b * 1024 + t * 4;
    int e0 = 0, e1 = 0, e2 = 0, e3 = 0;
    if (i0 + 4 <= n) {
        int4 v = *(const int4*)&cnt[i0];
        e0 = v.x; e1 = v.y; e2 = v.z; e3 = v.w;
    } else {
        if (i0 < n) e0 = cnt[i0];
        if (i0 + 1 < n) e1 = cnt[i0 + 1];
        if (i0 + 2 < n) e2 = cnt[i0 + 2];
        if (i0 + 3 < n) e3 = cnt[i0 + 3];
    }
    int tsum = e0 + e1 + e2 + e3;
    int incl = tsum;
    int lane = t & 63;
#pragma unroll
    for (int d = 1; d < 64; d <<= 1) {
        int u = __shfl_up(incl, d);
        if (lane >= d) incl += u;
    }
    __shared__ int wt[4];
    if (lane == 63) wt[t >> 6] = incl;
    __syncthreads();
    int w = t >> 6, wo = 0;
    for (int i = 0; i < w; ++i) wo += wt[i];
    int ex = incl - tsum + wo + bexcl[b];
    if (i0 < n) off[i0] = ex;
    if (i0 + 1 < n) off[i0 + 1] = ex + e0;
    if (i0 + 2 < n) off[i0 + 2] = ex + e0 + e1;
    if (i0 + 3 < n) off[i0 + 3] = ex + e0 + e1 + e2;
}

// scatter edges into CSR buckets; mutates off[] -> end-of-bucket
__global__ __launch_bounds__(256) void fill_kernel(const int* __restrict__ keys,
                                                   const int* __restrict__ vals, int E,
                                                   int* __restrict__ off,
                                                   int* __restrict__ idx) {
    int e = blockIdx.x * 256 + threadIdx.x;
    if (e >= E) return;
    int pos = atomicAdd(&off[keys[e]], 1);
    idx[pos] = vals[e];
}

// gather-mean: 32 lanes per dst row, float4 per lane.
__global__ __launch_bounds__(256) void gather_kernel(const float* __restrict__ feat,
                                                     const int* __restrict__ off,
                                                     const int* __restrict__ idx,
                                                     int n,
                                                     float* __restrict__ agg) {
    int row = blockIdx.x * 8 + (threadIdx.x >> 5);
    if (row >= n) return;
    int lane = (threadIdx.x & 31) * 4;
    int start = (row == 0) ? 0 : off[row - 1];
    int end = off[row];
    float4 a0 = make_float4(0.f, 0.f, 0.f, 0.f);
    float4 a1 = make_float4(0.f, 0.f, 0.f, 0.f);
    int j = start;
    for (; j + 2 <= end; j += 2) {
        int s0 = idx[j], s1 = idx[j + 1];
        float4 v0 = *(const float4*)&feat[(i64)s0 * H_ + lane];
        float4 v1 = *(const float4*)&feat[(i64)s1 * H_ + lane];
        a0.x += v0.x; a0.y += v0.y; a0.z += v0.z; a0.w += v0.w;
        a1.x += v1.x; a1.y += v1.y; a1.z += v1.z; a1.w += v1.w;
    }
    if (j < end) {
        int s0 = idx[j];
        float4 v0 = *(const float4*)&feat[(i64)s0 * H_ + lane];
        a0.x += v0.x; a0.y += v0.y; a0.z += v0.z; a0.w += v0.w;
    }
    float inv = 1.0f / fmaxf((float)(end - start), 1.0f);
    float4 o;
    o.x = (a0.x + a1.x) * inv;
    o.y = (a0.y + a1.y) * inv;
    o.z = (a0.z + a1.z) * inv;
    o.w = (a0.w + a1.w) * inv;
    *(float4*)&agg[(i64)row * H_ + lane] = o;
}

// ---- weight prep: W (fp32 [K][128], optionally sum of 3) -> WT hi/lo (bf16 [128][K]) ----
struct WJob {
    const float* s0; const float* s1; const float* s2;
    int logK; int base;
};
struct WJobs { WJob j[17]; };

__device__ __forceinline__ void split_bf16(float v, u16& h, u16& lo) {
    u32 b = __float_as_uint(v);
    h = (u16)(b >> 16);
    float rem = v - __uint_as_float(b & 0xffff0000u);
    lo = (u16)(__float_as_uint(rem) >> 16);
}

__global__ __launch_bounds__(256) void wsplit_kernel(WJobs jobs, int njobs, int total,
                                                     u16* __restrict__ WTH,
                                                     u16* __restrict__ WTL) {
    int gid = blockIdx.x * 256 + threadIdx.x;
    if (gid >= total) return;
    int ji = 0;
    for (int i = 1; i < 17; ++i)
        if (i < njobs && gid >= jobs.j[i].base) ji = i;
    WJob jb = jobs.j[ji];
    int local = gid - jb.base;
    int K = 1 << jb.logK;
    int n = local >> jb.logK;
    int k = local & (K - 1);
    i64 si = (i64)k * 128 + n;
    float v = jb.s0[si];
    if (jb.s1 != nullptr) v += jb.s1[si] + jb.s2[si];
    u16 h, lo;
    split_bf16(v, h, lo);
    WTH[gid] = h;
    WTL[gid] = lo;
}

// ---- MFMA GEMM: C = act( scale * (A1@W1 [+ A2@W2]) + bias_eff ) ----
// A row-major M x K fp32 (hi/lo split on the fly). W pre-split+transposed bf16 [128][K].
// 64 rows/block, 128 threads (2 waves), wave = 2 mtiles x 8 ntiles of 16x16x32 MFMA.
// 3-term split product: Ah@Wh + Al@Wh + Ah@Wl (error ~2^-15 rel, effectively fp32).
template <bool DUAL>
__global__ __launch_bounds__(128) void mgemm_kernel(
    const float* __restrict__ A1, int K1,
    const u16* __restrict__ W1h, const u16* __restrict__ W1l,
    const float* __restrict__ A2,
    const u16* __restrict__ W2h, const u16* __restrict__ W2l,
    const float* __restrict__ b1, const float* __restrict__ b2,
    float scale, int do_relu,
    float* __restrict__ C, int M) {
    __shared__ u16 AH[8192];  // 64 x 128 bf16, XOR-swizzled 16B slots
    __shared__ u16 AL[8192];
    int t = threadIdx.x;
    int w = t >> 6, l = t & 63;
    int lr = l & 15, lq = l >> 4;
    int m0 = blockIdx.x * 64;

    f32x4 acc[2][8];
#pragma unroll
    for (int mt = 0; mt < 2; ++mt)
#pragma unroll
        for (int nt = 0; nt < 8; ++nt) acc[mt][nt] = (f32x4){0.f, 0.f, 0.f, 0.f};

    const int nmat = DUAL ? 2 : 1;
    for (int mat = 0; mat < nmat; ++mat) {
        const float* A = (DUAL && mat) ? A2 : A1;
        const u16* Wh = (DUAL && mat) ? W2h : W1h;
        const u16* Wl = (DUAL && mat) ? W2l : W1l;
        int K = (DUAL && mat) ? H_ : K1;
        int nks = K >> 7;
        for (int ks = 0; ks < nks; ++ks) {
            const float* Ab = A + (i64)m0 * K + ks * 128;
            // stage 64x128 fp32 -> hi/lo bf16 LDS (coalesced float4 reads)
            for (int q = 0; q < 16; ++q) {
                int f = q * 512 + t * 4;
                int row = f >> 7, col = f & 127;
                float4 v = make_float4(0.f, 0.f, 0.f, 0.f);
                if (m0 + row < M) v = *(const float4*)&Ab[(i64)row * K + col];
                u16 h0, h1, h2, h3, q0, q1, q2, q3;
                split_bf16(v.x, h0, q0); split_bf16(v.y, h1, q1);
                split_bf16(v.z, h2, q2); split_bf16(v.w, h3, q3);
                uint2 uh, ul;
                uh.x = (u32)h0 | ((u32)h1 << 16); uh.y = (u32)h2 | ((u32)h3 << 16);
                ul.x = (u32)q0 | ((u32)q1 << 16); ul.y = (u32)q2 | ((u32)q3 << 16);
                int s = col >> 3, half = (col >> 2) & 1;
                int u16i = row * 128 + ((s ^ (row & 7)) << 3) + half * 4;
                *(uint2*)&AH[u16i] = uh;
                *(uint2*)&AL[u16i] = ul;
            }
            __syncthreads();
#pragma unroll
            for (int c = 0; c < 4; ++c) {
                int slot = c * 4 + lq;
                int r0 = w * 32 + lr;
                int r1 = r0 + 16;
                int i0 = r0 * 128 + ((slot ^ (r0 & 7)) << 3);
                int i1 = r1 * 128 + ((slot ^ (r1 & 7)) << 3);
                bf16x8 ah0 = *(const bf16x8*)&AH[i0];
                bf16x8 al0 = *(const bf16x8*)&AL[i0];
                bf16x8 ah1 = *(const bf16x8*)&AH[i1];
                bf16x8 al1 = *(const bf16x8*)&AL[i1];
                int kg = ks * 128 + c * 32 + (lq << 3);
#pragma unroll
                for (int nt = 0; nt < 8; ++nt) {
                    i64 widx = (i64)(nt * 16 + lr) * K + kg;
                    bf16x8 bh = *(const bf16x8*)&Wh[widx];
                    bf16x8 bl = *(const bf16x8*)&Wl[widx];
                    acc[0][nt] = __builtin_amdgcn_mfma_f32_16x16x32_bf16(ah0, bh, acc[0][nt], 0, 0, 0);
                    acc[1][nt] = __builtin_amdgcn_mfma_f32_16x16x32_bf16(ah1, bh, acc[1][nt], 0, 0, 0);
                    acc[0][nt] = __builtin_amdgcn_mfma_f32_16x16x32_bf16(al0, bh, acc[0][nt], 0, 0, 0);
                    acc[1][nt] = __builtin_amdgcn_mfma_f32_16x16x32_bf16(al1, bh, acc[1][nt], 0, 0, 0);
                    acc[0][nt] = __builtin_amdgcn_mfma_f32_16x16x32_bf16(ah0, bl, acc[0][nt], 0, 0, 0);
                    acc[1][nt] = __builtin_amdgcn_mfma_f32_16x16x32_bf16(ah1, bl, acc[1][nt], 0, 0, 0);
                }
            }
            __syncthreads();
        }
    }

    // epilogue: D lane mapping (verified): col = lane&15, row = (lane>>4)*4 + reg
#pragma unroll
    for (int nt = 0; nt < 8; ++nt) {
        int col = nt * 16 + lr;
        float bb = b1[col];
        if (DUAL) bb = 0.5f * (bb + b2[col]);
#pragma unroll
        for (int mt = 0; mt < 2; ++mt) {
#pragma unroll
            for (int r = 0; r < 4; ++r) {
                int row = m0 + w * 32 + mt * 16 + (lq << 2) + r;
                if (row < M) {
                    float o = acc[mt][nt][r] * scale + bb;
                    if (do_relu) o = fmaxf(o, 0.f);
                    C[(i64)row * H_ + col] = o;
                }
            }
        }
    }
}

__global__ __launch_bounds__(256) void fuse_kernel(const float* __restrict__ alpha,
                                                   const float* __restrict__ hui,
                                                   const float* __restrict__ hii,
                                                   const float* __restrict__ hia,
                                                   float* __restrict__ fused,
                                                   float* __restrict__ wout) {
    long i = (long)blockIdx.x * 256 + threadIdx.x;
    float a0 = alpha[0], a1 = alpha[1], a2 = alpha[2];
    float mx = fmaxf(a0, fmaxf(a1, a2));
    float e0 = expf(a0 - mx), e1 = expf(a1 - mx), e2 = expf(a2 - mx);
    float inv = 1.f / (e0 + e1 + e2);
    float w0 = e0 * inv, w1 = e1 * inv, w2 = e2 * inv;
    if (i == 0) { wout[0] = w0; wout[1] = w1; wout[2] = w2; }
    long n4 = (long)NI_ * H_ / 4;
    if (i < n4) {
        float4 u = ((const float4*)hui)[i];
        float4 v = ((const float4*)hii)[i];
        float4 t = ((const float4*)hia)[i];
        float4 o;
        o.x = w0 * u.x + w1 * v.x + w2 * t.x;
        o.y = w0 * u.y + w1 * v.y + w2 * t.y;
        o.z = w0 * u.z + w1 * v.z + w2 * t.z;
        o.w = w0 * u.w + w1 * v.w + w2 * t.w;
        ((float4*)fused)[i] = o;
    }
}

extern "C" void kernel_launch(void* const* d_in, const int* in_sizes, int n_in,
                              void* d_out, int out_size, void* d_ws, size_t ws_size,
                              hipStream_t stream) {
    const float* xif  = (const float*)d_in[0];
    const float* uemb = (const float*)d_in[1];
    const float* aemb = (const float*)d_in[2];
    const float* liW  = (const float*)d_in[3];
    const float* lib  = (const float*)d_in[4];
    const float* uiWl = (const float*)d_in[5];
    const float* uibl = (const float*)d_in[6];
    const float* uiWr = (const float*)d_in[7];
    const float* iiWl = (const float*)d_in[8];
    const float* iibl = (const float*)d_in[9];
    const float* iiWr = (const float*)d_in[10];
    const float* iaWl = (const float*)d_in[11];
    const float* iabl = (const float*)d_in[12];
    const float* iaWr = (const float*)d_in[13];
    const float* alpha = (const float*)d_in[14];
    const int* er = (const int*)d_in[15];
    const int* es = (const int*)d_in[16];
    const int* eh = (const int*)d_in[17];

    float* out = (float*)d_out;
    float* X      = out;                       // h_fused slot doubles as x_item scratch
    float* OUT_UI = out + (i64)NI_ * H_;
    float* OUT_II = out + (i64)2 * NI_ * H_;
    float* OUT_IA = out + (i64)3 * NI_ * H_;
    float* WOUT   = out + (i64)4 * NI_ * H_;

    float* ws = (float*)d_ws;
    i64 off = 0;
    float* HU1 = ws + off; off += (i64)NU_ * H_;
    float* HI1 = ws + off; off += (i64)NI_ * H_;
    float* AGG = ws + off; off += (i64)NU_ * H_;
    float* HA1 = ws + off; off += (i64)NA_ * H_;

    int* ip = (int*)(ws + off);
    i64 io = 0;
    int* off_ri = ip + io; io += NI_;
    int* off_ru = ip + io; io += NU_;
    int* off_si = ip + io; io += NI_;
    int* off_ha = ip + io; io += NA_;
    int* off_hi = ip + io; io += NI_;
    int* idx_ri = ip + io; io += ER_;
    int* idx_ru = ip + io; io += ER_;
    int* idx_si = ip + io; io += ES_;
    int* idx_ha = ip + io; io += EH_;
    int* idx_hi = ip + io; io += EH_;
    int* CNTI   = ip + io; io += NU_;
    int* BSUM   = ip + io; io += 128;

    u16* WTH = (u16*)(ip + io);           // 294912 u16
    u16* WTL = WTH + 294912;

    auto fill0i = [&](int* p, long nints) {
        long n4 = nints / 4;
        fillz_kernel<<<(int)((n4 + 255) / 256), 256, 0, stream>>>((float4*)p, n4);
    };

    auto build_csr = [&](const int* keys, const int* vals, int E, int n,
                         int* offx, int* idxx) {
        int nb = (n + 1023) / 1024;
        fill0i(CNTI, n);
        count_kernel<<<(E + 255) / 256, 256, 0, stream>>>(keys, E, CNTI);
        bsum_kernel<<<nb, 256, 0, stream>>>(CNTI, n, BSUM);
        scan_top_kernel<<<1, 128, 0, stream>>>(BSUM, nb);
        scan_block_kernel<<<nb, 256, 0, stream>>>(CNTI, n, BSUM, offx);
        fill_kernel<<<(E + 255) / 256, 256, 0, stream>>>(keys, vals, E, offx, idxx);
    };

    build_csr(er + ER_, er,       ER_, NI_, off_ri, idx_ri);
    build_csr(er,       er + ER_, ER_, NU_, off_ru, idx_ru);
    build_csr(es + ES_, es,       ES_, NI_, off_si, idx_si);
    build_csr(eh + EH_, eh,       EH_, NA_, off_ha, idx_ha);
    build_csr(eh,       eh + EH_, EH_, NI_, off_hi, idx_hi);

    // ---- weight split/transpose jobs ----
    // dual slots: (family Wl/Wr, edge idx e, self idx s_)
    const float* famWl[8] = {uiWl, uiWl, uiWl, iiWl, iiWl, iaWl, iaWl, iaWl};
    const float* famWr[8] = {uiWr, uiWr, uiWr, iiWr, iiWr, iaWr, iaWr, iaWr};
    const float* famBl[8] = {uibl, uibl, uibl, iibl, iibl, iabl, iabl, iabl};
    const int eidx[8] = {0, 1, 4, 0, 2, 0, 1, 5};
    const int sidx[8] = {3, 2, 7, 1, 3, 3, 2, 6};

    WJobs jobs;
    jobs.j[0] = {liW, nullptr, nullptr, 8, 0};
    int base = 32768;
    for (int s = 0; s < 8; ++s) {
        jobs.j[1 + 2 * s] = {famWl[s] + (i64)eidx[s] * 16384, nullptr, nullptr, 7, base};
        base += 16384;
        jobs.j[2 + 2 * s] = {famWr[s] + (i64)eidx[s] * 16384,
                             famWl[s] + (i64)sidx[s] * 16384,
                             famWr[s] + (i64)sidx[s] * 16384, 7, base};
        base += 16384;
    }
    int total = base;  // 294912
    wsplit_kernel<<<(total + 255) / 256, 256, 0, stream>>>(jobs, 17, total, WTH, WTL);

    // x_item = xif @ liW + lib   (no relu)
    mgemm_kernel<false><<<(NI_ + 63) / 64, 128, 0, stream>>>(
        xif, FEAT_, WTH, WTL, nullptr, nullptr, nullptr,
        lib, nullptr, 1.0f, 0, X, NI_);

    auto agg_run = [&](const float* feat, const int* offx, const int* idxx, int ndst) {
        gather_kernel<<<(ndst + 7) / 8, 256, 0, stream>>>(feat, offx, idxx, ndst, AGG);
    };
    auto gemm2 = [&](int slot, const float* A2m, float* Cout, int M) {
        const u16* w1h = WTH + 32768 + (i64)(2 * slot) * 16384;
        const u16* w1l = WTL + 32768 + (i64)(2 * slot) * 16384;
        const u16* w2h = WTH + 32768 + (i64)(2 * slot + 1) * 16384;
        const u16* w2l = WTL + 32768 + (i64)(2 * slot + 1) * 16384;
        const float* be = famBl[slot] + (i64)eidx[slot] * 128;
        const float* bs = famBl[slot] + (i64)sidx[slot] * 128;
        mgemm_kernel<true><<<(M + 63) / 64, 128, 0, stream>>>(
            AGG, H_, w1h, w1l, A2m, w2h, w2l, be, bs, 0.5f, 1, Cout, M);
    };

    // ---- UI branch ----
    agg_run(uemb, off_ri, idx_ri, NI_);
    gemm2(0, X, HI1, NI_);
    agg_run(X, off_ru, idx_ru, NU_);
    gemm2(1, uemb, HU1, NU_);
    agg_run(HU1, off_ri, idx_ri, NI_);              // L1 o_i only (o_u dead)
    gemm2(2, HI1, OUT_UI, NI_);

    // ---- II branch ----
    agg_run(X, off_si, idx_si, NI_);
    gemm2(3, X, HI1, NI_);
    agg_run(HI1, off_si, idx_si, NI_);
    gemm2(4, HI1, OUT_II, NI_);

    // ---- IA branch ----
    agg_run(X, off_ha, idx_ha, NA_);
    gemm2(5, aemb, HA1, NA_);
    agg_run(aemb, off_hi, idx_hi, NI_);
    gemm2(6, X, HI1, NI_);
    agg_run(HA1, off_hi, idx_hi, NI_);              // L1 o_i only (o_a dead)
    gemm2(7, HI1, OUT_IA, NI_);

    // ---- fuse ----
    long n4 = (long)NI_ * H_ / 4;
    fuse_kernel<<<(int)((n4 + 255) / 256), 256, 0, stream>>>(
        alpha, OUT_UI, OUT_II, OUT_IA, X, WOUT);
}

// Round 5
// 1023.075 us; speedup vs baseline: 8.8337x; 1.1818x over previous
//
#include <hip/hip_runtime.h>

#define NU_ 100000
#define NI_ 50000
#define NA_ 5000
#define FEAT_ 256
#define H_ 128
#define ER_ 1000000
#define ES_ 500000
#define EH_ 250000

typedef long long i64;
typedef unsigned short u16;
typedef unsigned int u32;
typedef __attribute__((ext_vector_type(8))) short bf16x8;
typedef __attribute__((ext_vector_type(4))) float f32x4;

__global__ __launch_bounds__(256) void fillz_kernel(float4* __restrict__ p, long n4) {
    long i = (long)blockIdx.x * 256 + threadIdx.x;
    if (i < n4) p[i] = make_float4(0.f, 0.f, 0.f, 0.f);
}

// count occurrences of keys
__global__ __launch_bounds__(256) void count_kernel(const int* __restrict__ keys, int E,
                                                    int* __restrict__ cnt) {
    int e = blockIdx.x * 256 + threadIdx.x;
    if (e >= E) return;
    atomicAdd(&cnt[keys[e]], 1);
}

// ---- 3-phase device-wide exclusive scan over cnt[0..n) ----
__global__ __launch_bounds__(256) void bsum_kernel(const int* __restrict__ cnt, int n,
                                                   int* __restrict__ bsum) {
    int b = blockIdx.x, t = threadIdx.x;
    long i0 = (long)b * 1024 + t * 4;
    int s = 0;
    if (i0 + 4 <= n) {
        int4 v = *(const int4*)&cnt[i0];
        s = v.x + v.y + v.z + v.w;
    } else {
#pragma unroll
        for (int k = 0; k < 4; ++k)
            if (i0 + k < n) s += cnt[i0 + k];
    }
#pragma unroll
    for (int d = 32; d; d >>= 1) s += __shfl_down(s, d);
    __shared__ int ws[4];
    if ((t & 63) == 0) ws[t >> 6] = s;
    __syncthreads();
    if (t == 0) bsum[b] = ws[0] + ws[1] + ws[2] + ws[3];
}

__global__ __launch_bounds__(128) void scan_top_kernel(int* __restrict__ bsum, int nb) {
    int t = threadIdx.x;
    int v = (t < nb) ? bsum[t] : 0;
    int incl = v;
    int lane = t & 63;
#pragma unroll
    for (int d = 1; d < 64; d <<= 1) {
        int u = __shfl_up(incl, d);
        if (lane >= d) incl += u;
    }
    __shared__ int w0;
    if (t == 63) w0 = incl;
    __syncthreads();
    int ex = incl - v + ((t >= 64) ? w0 : 0);
    if (t < nb) bsum[t] = ex;
}

__global__ __launch_bounds__(256) void scan_block_kernel(const int* __restrict__ cnt, int n,
                                                         const int* __restrict__ bexcl,
                                                         int* __restrict__ off) {
    int b = blockIdx.x, t = threadIdx.x;
    long i0 = (long)b * 1024 + t * 4;
    int e0 = 0, e1 = 0, e2 = 0, e3 = 0;
    if (i0 + 4 <= n) {
        int4 v = *(const int4*)&cnt[i0];
        e0 = v.x; e1 = v.y; e2 = v.z; e3 = v.w;
    } else {
        if (i0 < n) e0 = cnt[i0];
        if (i0 + 1 < n) e1 = cnt[i0 + 1];
        if (i0 + 2 < n) e2 = cnt[i0 + 2];
        if (i0 + 3 < n) e3 = cnt[i0 + 3];
    }
    int tsum = e0 + e1 + e2 + e3;
    int incl = tsum;
    int lane = t & 63;
#pragma unroll
    for (int d = 1; d < 64; d <<= 1) {
        int u = __shfl_up(incl, d);
        if (lane >= d) incl += u;
    }
    __shared__ int wt[4];
    if (lane == 63) wt[t >> 6] = incl;
    __syncthreads();
    int w = t >> 6, wo = 0;
    for (int i = 0; i < w; ++i) wo += wt[i];
    int ex = incl - tsum + wo + bexcl[b];
    if (i0 < n) off[i0] = ex;
    if (i0 + 1 < n) off[i0 + 1] = ex + e0;
    if (i0 + 2 < n) off[i0 + 2] = ex + e0 + e1;
    if (i0 + 3 < n) off[i0 + 3] = ex + e0 + e1 + e2;
}

// scatter edges into CSR buckets; mutates off[] -> end-of-bucket
__global__ __launch_bounds__(256) void fill_kernel(const int* __restrict__ keys,
                                                   const int* __restrict__ vals, int E,
                                                   int* __restrict__ off,
                                                   int* __restrict__ idx) {
    int e = blockIdx.x * 256 + threadIdx.x;
    if (e >= E) return;
    int pos = atomicAdd(&off[keys[e]], 1);
    idx[pos] = vals[e];
}

// gather-mean: 32 lanes per dst row, float4 per lane.
__global__ __launch_bounds__(256) void gather_kernel(const float* __restrict__ feat,
                                                     const int* __restrict__ off,
                                                     const int* __restrict__ idx,
                                                     int n,
                                                     float* __restrict__ agg) {
    int row = blockIdx.x * 8 + (threadIdx.x >> 5);
    if (row >= n) return;
    int lane = (threadIdx.x & 31) * 4;
    int start = (row == 0) ? 0 : off[row - 1];
    int end = off[row];
    float4 a0 = make_float4(0.f, 0.f, 0.f, 0.f);
    float4 a1 = make_float4(0.f, 0.f, 0.f, 0.f);
    int j = start;
    for (; j + 2 <= end; j += 2) {
        int s0 = idx[j], s1 = idx[j + 1];
        float4 v0 = *(const float4*)&feat[(i64)s0 * H_ + lane];
        float4 v1 = *(const float4*)&feat[(i64)s1 * H_ + lane];
        a0.x += v0.x; a0.y += v0.y; a0.z += v0.z; a0.w += v0.w;
        a1.x += v1.x; a1.y += v1.y; a1.z += v1.z; a1.w += v1.w;
    }
    if (j < end) {
        int s0 = idx[j];
        float4 v0 = *(const float4*)&feat[(i64)s0 * H_ + lane];
        a0.x += v0.x; a0.y += v0.y; a0.z += v0.z; a0.w += v0.w;
    }
    float inv = 1.0f / fmaxf((float)(end - start), 1.0f);
    float4 o;
    o.x = (a0.x + a1.x) * inv;
    o.y = (a0.y + a1.y) * inv;
    o.z = (a0.z + a1.z) * inv;
    o.w = (a0.w + a1.w) * inv;
    *(float4*)&agg[(i64)row * H_ + lane] = o;
}

// ---- weight prep: W (fp32 [K][128], optionally sum of 3) -> frag-tiled hi/lo bf16 ----
// frag layout: index = ((kc*8 + nt)*64 + l)*8 + e  holds  W_T[n=nt*16+(l&15)][k=kc*32+((l>>4)<<3)+e]
struct WJob {
    const float* s0; const float* s1; const float* s2;
    int logK; int base;
};
struct WJobs { WJob j[17]; };

__device__ __forceinline__ void split_bf16(float v, u16& h, u16& lo) {
    u32 b = __float_as_uint(v);
    h = (u16)(b >> 16);
    float rem = v - __uint_as_float(b & 0xffff0000u);
    lo = (u16)(__float_as_uint(rem) >> 16);
}

__global__ __launch_bounds__(256) void wsplit_kernel(WJobs jobs, int njobs, int total,
                                                     u16* __restrict__ WTH,
                                                     u16* __restrict__ WTL) {
    int gid = blockIdx.x * 256 + threadIdx.x;
    if (gid >= total) return;
    int ji = 0;
    for (int i = 1; i < 17; ++i)
        if (i < njobs && gid >= jobs.j[i].base) ji = i;
    WJob jb = jobs.j[ji];
    int local = gid - jb.base;
    int e = local & 7;
    int l = (local >> 3) & 63;
    int nt = (local >> 9) & 7;
    int kc = local >> 12;
    int n = nt * 16 + (l & 15);
    int k = kc * 32 + ((l >> 4) << 3) + e;
    i64 si = (i64)k * 128 + n;
    float v = jb.s0[si];
    if (jb.s1 != nullptr) v += jb.s1[si] + jb.s2[si];
    u16 h, lo;
    split_bf16(v, h, lo);
    WTH[gid] = h;
    WTL[gid] = lo;
}

__device__ __forceinline__ void split8(const float* f, bf16x8& h, bf16x8& lo) {
#pragma unroll
    for (int i = 0; i < 8; ++i) {
        u32 b = __float_as_uint(f[i]);
        h[i] = (short)(u16)(b >> 16);
        float rem = f[i] - __uint_as_float(b & 0xffff0000u);
        lo[i] = (short)(u16)(__float_as_uint(rem) >> 16);
    }
}

// ---- LDS-free MFMA GEMM: C = act( scale * (A1@W1 [+ A2@W2]) + bias_eff ) ----
// A row-major M x K fp32; per-lane direct frag loads (2x float4) + in-register hi/lo split.
// W pre-split + frag-tiled (see wsplit). 256 thr = 4 waves; wave owns 32 rows x 128 cols.
// 3-term split product: Ah@Wh + Al@Wh + Ah@Wl (~fp32 accuracy). No LDS, no barriers.
template <bool DUAL>
__global__ __launch_bounds__(256) void mgemm_kernel(
    const float* __restrict__ A1, int K1,
    const u16* __restrict__ W1h, const u16* __restrict__ W1l,
    const float* __restrict__ A2,
    const u16* __restrict__ W2h, const u16* __restrict__ W2l,
    const float* __restrict__ b1, const float* __restrict__ b2,
    float scale, int do_relu,
    float* __restrict__ C, int M) {
    int t = threadIdx.x;
    int w = t >> 6, l = t & 63;
    int lr = l & 15, lq = l >> 4;
    int m0 = blockIdx.x * 128 + w * 32;

    f32x4 acc[2][8];
#pragma unroll
    for (int mt = 0; mt < 2; ++mt)
#pragma unroll
        for (int nt = 0; nt < 8; ++nt) acc[mt][nt] = (f32x4){0.f, 0.f, 0.f, 0.f};

    const int nmat = DUAL ? 2 : 1;
    for (int mat = 0; mat < nmat; ++mat) {
        const float* A = (DUAL && mat) ? A2 : A1;
        const u16* Wh = (DUAL && mat) ? W2h : W1h;
        const u16* Wl = (DUAL && mat) ? W2l : W1l;
        const int K = (DUAL && mat) ? H_ : K1;
        const int nkc = K >> 5;
        for (int kc = 0; kc < nkc; ++kc) {
            bf16x8 ah0, al0, ah1, al1;
            {
                int row = m0 + lr;
                float f[8];
                if (row < M) {
                    const float* ap = &A[(i64)row * K + kc * 32 + lq * 8];
                    *(float4*)&f[0] = *(const float4*)ap;
                    *(float4*)&f[4] = *(const float4*)(ap + 4);
                } else {
#pragma unroll
                    for (int i = 0; i < 8; ++i) f[i] = 0.f;
                }
                split8(f, ah0, al0);
            }
            {
                int row = m0 + 16 + lr;
                float f[8];
                if (row < M) {
                    const float* ap = &A[(i64)row * K + kc * 32 + lq * 8];
                    *(float4*)&f[0] = *(const float4*)ap;
                    *(float4*)&f[4] = *(const float4*)(ap + 4);
                } else {
#pragma unroll
                    for (int i = 0; i < 8; ++i) f[i] = 0.f;
                }
                split8(f, ah1, al1);
            }
            const u16* whp = Wh + ((i64)kc * 8) * 512 + (i64)l * 8;
            const u16* wlp = Wl + ((i64)kc * 8) * 512 + (i64)l * 8;
#pragma unroll
            for (int nt = 0; nt < 8; ++nt) {
                bf16x8 bh = *(const bf16x8*)(whp + nt * 512);
                bf16x8 bl = *(const bf16x8*)(wlp + nt * 512);
                acc[0][nt] = __builtin_amdgcn_mfma_f32_16x16x32_bf16(ah0, bh, acc[0][nt], 0, 0, 0);
                acc[1][nt] = __builtin_amdgcn_mfma_f32_16x16x32_bf16(ah1, bh, acc[1][nt], 0, 0, 0);
                acc[0][nt] = __builtin_amdgcn_mfma_f32_16x16x32_bf16(al0, bh, acc[0][nt], 0, 0, 0);
                acc[1][nt] = __builtin_amdgcn_mfma_f32_16x16x32_bf16(al1, bh, acc[1][nt], 0, 0, 0);
                acc[0][nt] = __builtin_amdgcn_mfma_f32_16x16x32_bf16(ah0, bl, acc[0][nt], 0, 0, 0);
                acc[1][nt] = __builtin_amdgcn_mfma_f32_16x16x32_bf16(ah1, bl, acc[1][nt], 0, 0, 0);
            }
        }
    }

    // epilogue: D lane mapping: col = lane&15, row = (lane>>4)*4 + reg
#pragma unroll
    for (int nt = 0; nt < 8; ++nt) {
        int col = nt * 16 + lr;
        float bb = b1[col];
        if (DUAL) bb = 0.5f * (bb + b2[col]);
#pragma unroll
        for (int mt = 0; mt < 2; ++mt) {
#pragma unroll
            for (int r = 0; r < 4; ++r) {
                int row = m0 + mt * 16 + (lq << 2) + r;
                if (row < M) {
                    float o = acc[mt][nt][r] * scale + bb;
                    if (do_relu) o = fmaxf(o, 0.f);
                    C[(i64)row * H_ + col] = o;
                }
            }
        }
    }
}

__global__ __launch_bounds__(256) void fuse_kernel(const float* __restrict__ alpha,
                                                   const float* __restrict__ hui,
                                                   const float* __restrict__ hii,
                                                   const float* __restrict__ hia,
                                                   float* __restrict__ fused,
                                                   float* __restrict__ wout) {
    long i = (long)blockIdx.x * 256 + threadIdx.x;
    float a0 = alpha[0], a1 = alpha[1], a2 = alpha[2];
    float mx = fmaxf(a0, fmaxf(a1, a2));
    float e0 = expf(a0 - mx), e1 = expf(a1 - mx), e2 = expf(a2 - mx);
    float inv = 1.f / (e0 + e1 + e2);
    float w0 = e0 * inv, w1 = e1 * inv, w2 = e2 * inv;
    if (i == 0) { wout[0] = w0; wout[1] = w1; wout[2] = w2; }
    long n4 = (long)NI_ * H_ / 4;
    if (i < n4) {
        float4 u = ((const float4*)hui)[i];
        float4 v = ((const float4*)hii)[i];
        float4 t = ((const float4*)hia)[i];
        float4 o;
        o.x = w0 * u.x + w1 * v.x + w2 * t.x;
        o.y = w0 * u.y + w1 * v.y + w2 * t.y;
        o.z = w0 * u.z + w1 * v.z + w2 * t.z;
        o.w = w0 * u.w + w1 * v.w + w2 * t.w;
        ((float4*)fused)[i] = o;
    }
}

extern "C" void kernel_launch(void* const* d_in, const int* in_sizes, int n_in,
                              void* d_out, int out_size, void* d_ws, size_t ws_size,
                              hipStream_t stream) {
    const float* xif  = (const float*)d_in[0];
    const float* uemb = (const float*)d_in[1];
    const float* aemb = (const float*)d_in[2];
    const float* liW  = (const float*)d_in[3];
    const float* lib  = (const float*)d_in[4];
    const float* uiWl = (const float*)d_in[5];
    const float* uibl = (const float*)d_in[6];
    const float* uiWr = (const float*)d_in[7];
    const float* iiWl = (const float*)d_in[8];
    const float* iibl = (const float*)d_in[9];
    const float* iiWr = (const float*)d_in[10];
    const float* iaWl = (const float*)d_in[11];
    const float* iabl = (const float*)d_in[12];
    const float* iaWr = (const float*)d_in[13];
    const float* alpha = (const float*)d_in[14];
    const int* er = (const int*)d_in[15];
    const int* es = (const int*)d_in[16];
    const int* eh = (const int*)d_in[17];

    float* out = (float*)d_out;
    float* X      = out;                       // h_fused slot doubles as x_item scratch
    float* OUT_UI = out + (i64)NI_ * H_;
    float* OUT_II = out + (i64)2 * NI_ * H_;
    float* OUT_IA = out + (i64)3 * NI_ * H_;
    float* WOUT   = out + (i64)4 * NI_ * H_;

    float* ws = (float*)d_ws;
    i64 off = 0;
    float* HU1 = ws + off; off += (i64)NU_ * H_;
    float* HI1 = ws + off; off += (i64)NI_ * H_;
    float* AGG = ws + off; off += (i64)NU_ * H_;
    float* HA1 = ws + off; off += (i64)NA_ * H_;

    int* ip = (int*)(ws + off);
    i64 io = 0;
    int* off_ri = ip + io; io += NI_;
    int* off_ru = ip + io; io += NU_;
    int* off_si = ip + io; io += NI_;
    int* off_ha = ip + io; io += NA_;
    int* off_hi = ip + io; io += NI_;
    int* idx_ri = ip + io; io += ER_;
    int* idx_ru = ip + io; io += ER_;
    int* idx_si = ip + io; io += ES_;
    int* idx_ha = ip + io; io += EH_;
    int* idx_hi = ip + io; io += EH_;
    int* CNTI   = ip + io; io += NU_;
    int* BSUM   = ip + io; io += 128;

    u16* WTH = (u16*)(ip + io);           // 294912 u16
    u16* WTL = WTH + 294912;

    auto fill0i = [&](int* p, long nints) {
        long n4 = nints / 4;
        fillz_kernel<<<(int)((n4 + 255) / 256), 256, 0, stream>>>((float4*)p, n4);
    };

    auto build_csr = [&](const int* keys, const int* vals, int E, int n,
                         int* offx, int* idxx) {
        int nb = (n + 1023) / 1024;
        fill0i(CNTI, n);
        count_kernel<<<(E + 255) / 256, 256, 0, stream>>>(keys, E, CNTI);
        bsum_kernel<<<nb, 256, 0, stream>>>(CNTI, n, BSUM);
        scan_top_kernel<<<1, 128, 0, stream>>>(BSUM, nb);
        scan_block_kernel<<<nb, 256, 0, stream>>>(CNTI, n, BSUM, offx);
        fill_kernel<<<(E + 255) / 256, 256, 0, stream>>>(keys, vals, E, offx, idxx);
    };

    build_csr(er + ER_, er,       ER_, NI_, off_ri, idx_ri);
    build_csr(er,       er + ER_, ER_, NU_, off_ru, idx_ru);
    build_csr(es + ES_, es,       ES_, NI_, off_si, idx_si);
    build_csr(eh + EH_, eh,       EH_, NA_, off_ha, idx_ha);
    build_csr(eh,       eh + EH_, EH_, NI_, off_hi, idx_hi);

    // ---- weight split/transpose jobs ----
    const float* famWl[8] = {uiWl, uiWl, uiWl, iiWl, iiWl, iaWl, iaWl, iaWl};
    const float* famWr[8] = {uiWr, uiWr, uiWr, iiWr, iiWr, iaWr, iaWr, iaWr};
    const float* famBl[8] = {uibl, uibl, uibl, iibl, iibl, iabl, iabl, iabl};
    const int eidx[8] = {0, 1, 4, 0, 2, 0, 1, 5};
    const int sidx[8] = {3, 2, 7, 1, 3, 3, 2, 6};

    WJobs jobs;
    jobs.j[0] = {liW, nullptr, nullptr, 8, 0};
    int base = 32768;
    for (int s = 0; s < 8; ++s) {
        jobs.j[1 + 2 * s] = {famWl[s] + (i64)eidx[s] * 16384, nullptr, nullptr, 7, base};
        base += 16384;
        jobs.j[2 + 2 * s] = {famWr[s] + (i64)eidx[s] * 16384,
                             famWl[s] + (i64)sidx[s] * 16384,
                             famWr[s] + (i64)sidx[s] * 16384, 7, base};
        base += 16384;
    }
    int total = base;  // 294912
    wsplit_kernel<<<(total + 255) / 256, 256, 0, stream>>>(jobs, 17, total, WTH, WTL);

    // x_item = xif @ liW + lib   (no relu)
    mgemm_kernel<false><<<(NI_ + 127) / 128, 256, 0, stream>>>(
        xif, FEAT_, WTH, WTL, nullptr, nullptr, nullptr,
        lib, nullptr, 1.0f, 0, X, NI_);

    auto agg_run = [&](const float* feat, const int* offx, const int* idxx, int ndst) {
        gather_kernel<<<(ndst + 7) / 8, 256, 0, stream>>>(feat, offx, idxx, ndst, AGG);
    };
    auto gemm2 = [&](int slot, const float* A2m, float* Cout, int M) {
        const u16* w1h = WTH + 32768 + (i64)(2 * slot) * 16384;
        const u16* w1l = WTL + 32768 + (i64)(2 * slot) * 16384;
        const u16* w2h = WTH + 32768 + (i64)(2 * slot + 1) * 16384;
        const u16* w2l = WTL + 32768 + (i64)(2 * slot + 1) * 16384;
        const float* be = famBl[slot] + (i64)eidx[slot] * 128;
        const float* bs = famBl[slot] + (i64)sidx[slot] * 128;
        mgemm_kernel<true><<<(M + 127) / 128, 256, 0, stream>>>(
            AGG, H_, w1h, w1l, A2m, w2h, w2l, be, bs, 0.5f, 1, Cout, M);
    };

    // ---- UI branch ----
    agg_run(uemb, off_ri, idx_ri, NI_);
    gemm2(0, X, HI1, NI_);
    agg_run(X, off_ru, idx_ru, NU_);
    gemm2(1, uemb, HU1, NU_);
    agg_run(HU1, off_ri, idx_ri, NI_);              // L1 o_i only (o_u dead)
    gemm2(2, HI1, OUT_UI, NI_);

    // ---- II branch ----
    agg_run(X, off_si, idx_si, NI_);
    gemm2(3, X, HI1, NI_);
    agg_run(HI1, off_si, idx_si, NI_);
    gemm2(4, HI1, OUT_II, NI_);

    // ---- IA branch ----
    agg_run(X, off_ha, idx_ha, NA_);
    gemm2(5, aemb, HA1, NA_);
    agg_run(aemb, off_hi, idx_hi, NI_);
    gemm2(6, X, HI1, NI_);
    agg_run(HA1, off_hi, idx_hi, NI_);              // L1 o_i only (o_a dead)
    gemm2(7, HI1, OUT_IA, NI_);

    // ---- fuse ----
    long n4 = (long)NI_ * H_ / 4;
    fuse_kernel<<<(int)((n4 + 255) / 256), 256, 0, stream>>>(
        alpha, OUT_UI, OUT_II, OUT_IA, X, WOUT);
}

// Round 6
// 896.076 us; speedup vs baseline: 10.0857x; 1.1417x over previous
//
#include <hip/hip_runtime.h>

#define NU_ 100000
#define NI_ 50000
#define NA_ 5000
#define FEAT_ 256
#define H_ 128
#define ER_ 1000000
#define ES_ 500000
#define EH_ 250000

#define NTOT_ (3 * NI_ + NU_ + NA_)      // 255000 combined counters
#define ETOT_ (ER_ + ES_ + EH_)          // 1,750,000 edges
// counter-array bases (order defines pool layout via global scan)
#define B_RI 0
#define B_RU (NI_)
#define B_SI (NI_ + NU_)
#define B_HA (2 * NI_ + NU_)
#define B_HI (2 * NI_ + NU_ + NA_)

typedef long long i64;
typedef unsigned short u16;
typedef unsigned int u32;
typedef __attribute__((ext_vector_type(8))) short bf16x8;
typedef __attribute__((ext_vector_type(4))) float f32x4;

__device__ __forceinline__ u16 f2bf(float v) {           // round-to-nearest-even
    u32 b = __float_as_uint(v);
    b += 0x7fff + ((b >> 16) & 1);
    return (u16)(b >> 16);
}
__device__ __forceinline__ float bf2f(u16 v) {
    return __uint_as_float((u32)v << 16);
}

__global__ __launch_bounds__(256) void fillz_kernel(float4* __restrict__ p, long n4) {
    long i = (long)blockIdx.x * 256 + threadIdx.x;
    if (i < n4) p[i] = make_float4(0.f, 0.f, 0.f, 0.f);
}

// fp32 -> bf16 table convert
__global__ __launch_bounds__(256) void tobf_kernel(const float4* __restrict__ in,
                                                   ushort4* __restrict__ out, long n4) {
    long i = (long)blockIdx.x * 256 + threadIdx.x;
    if (i >= n4) return;
    float4 v = in[i];
    ushort4 o;
    o.x = f2bf(v.x); o.y = f2bf(v.y); o.z = f2bf(v.z); o.w = f2bf(v.w);
    out[i] = o;
}

// ---- fused CSR build over all 5 graphs ----
__global__ __launch_bounds__(256) void countall_kernel(const int* __restrict__ er,
                                                       const int* __restrict__ es,
                                                       const int* __restrict__ eh,
                                                       int* __restrict__ cnt) {
    int g = blockIdx.x * 256 + threadIdx.x;
    if (g < ER_) {
        atomicAdd(&cnt[B_RI + er[ER_ + g]], 1);
        atomicAdd(&cnt[B_RU + er[g]], 1);
    } else if (g < ER_ + ES_) {
        int e = g - ER_;
        atomicAdd(&cnt[B_SI + es[ES_ + e]], 1);
    } else if (g < ETOT_) {
        int e = g - ER_ - ES_;
        atomicAdd(&cnt[B_HA + eh[EH_ + e]], 1);
        atomicAdd(&cnt[B_HI + eh[e]], 1);
    }
}

__global__ __launch_bounds__(256) void bsum_kernel(const int* __restrict__ cnt, int n,
                                                   int* __restrict__ bsum) {
    int b = blockIdx.x, t = threadIdx.x;
    long i0 = (long)b * 1024 + t * 4;
    int s = 0;
    if (i0 + 4 <= n) {
        int4 v = *(const int4*)&cnt[i0];
        s = v.x + v.y + v.z + v.w;
    } else {
#pragma unroll
        for (int k = 0; k < 4; ++k)
            if (i0 + k < n) s += cnt[i0 + k];
    }
#pragma unroll
    for (int d = 32; d; d >>= 1) s += __shfl_down(s, d);
    __shared__ int ws[4];
    if ((t & 63) == 0) ws[t >> 6] = s;
    __syncthreads();
    if (t == 0) bsum[b] = ws[0] + ws[1] + ws[2] + ws[3];
}

// single block, 256 threads, scans nb <= 256 chunk totals -> exclusive
__global__ __launch_bounds__(256) void scan_top_kernel(int* __restrict__ bsum, int nb) {
    int t = threadIdx.x;
    int v = (t < nb) ? bsum[t] : 0;
    int incl = v;
    int lane = t & 63;
#pragma unroll
    for (int d = 1; d < 64; d <<= 1) {
        int u = __shfl_up(incl, d);
        if (lane >= d) incl += u;
    }
    __shared__ int wt[4];
    if (lane == 63) wt[t >> 6] = incl;
    __syncthreads();
    int add = 0;
    for (int i = 0; i < (t >> 6); ++i) add += wt[i];
    if (t < nb) bsum[t] = incl - v + add;
}

__global__ __launch_bounds__(256) void scan_block_kernel(const int* __restrict__ cnt, int n,
                                                         const int* __restrict__ bexcl,
                                                         int* __restrict__ off1) {
    int b = blockIdx.x, t = threadIdx.x;
    long i0 = (long)b * 1024 + t * 4;
    int e0 = 0, e1 = 0, e2 = 0, e3 = 0;
    if (i0 + 4 <= n) {
        int4 v = *(const int4*)&cnt[i0];
        e0 = v.x; e1 = v.y; e2 = v.z; e3 = v.w;
    } else {
        if (i0 < n) e0 = cnt[i0];
        if (i0 + 1 < n) e1 = cnt[i0 + 1];
        if (i0 + 2 < n) e2 = cnt[i0 + 2];
        if (i0 + 3 < n) e3 = cnt[i0 + 3];
    }
    int tsum = e0 + e1 + e2 + e3;
    int incl = tsum;
    int lane = t & 63;
#pragma unroll
    for (int d = 1; d < 64; d <<= 1) {
        int u = __shfl_up(incl, d);
        if (lane >= d) incl += u;
    }
    __shared__ int wt[4];
    if (lane == 63) wt[t >> 6] = incl;
    __syncthreads();
    int w = t >> 6, wo = 0;
    for (int i = 0; i < w; ++i) wo += wt[i];
    int ex = incl - tsum + wo + bexcl[b];
    if (i0 < n) off1[i0] = ex;
    if (i0 + 1 < n) off1[i0 + 1] = ex + e0;
    if (i0 + 2 < n) off1[i0 + 2] = ex + e0 + e1;
    if (i0 + 3 < n) off1[i0 + 3] = ex + e0 + e1 + e2;
}

// scatter all edges into the combined pool; mutates off1[] -> end-of-bucket
__global__ __launch_bounds__(256) void fillall_kernel(const int* __restrict__ er,
                                                      const int* __restrict__ es,
                                                      const int* __restrict__ eh,
                                                      int* __restrict__ off1,
                                                      int* __restrict__ pool) {
    int g = blockIdx.x * 256 + threadIdx.x;
    if (g < ER_) {
        int u = er[g], it = er[ER_ + g];
        pool[atomicAdd(&off1[B_RI + it], 1)] = u;
        pool[atomicAdd(&off1[B_RU + u], 1)] = it;
    } else if (g < ER_ + ES_) {
        int e = g - ER_;
        pool[atomicAdd(&off1[B_SI + es[ES_ + e]], 1)] = es[e];
    } else if (g < ETOT_) {
        int e = g - ER_ - ES_;
        pool[atomicAdd(&off1[B_HA + eh[EH_ + e]], 1)] = eh[e];
        pool[atomicAdd(&off1[B_HI + eh[e]], 1)] = eh[EH_ + e];
    }
}

// gather-mean over bf16 features: 32 lanes per dst row, ushort4 (4 cols) per lane.
// off1 points at this CSR's base inside the global cursor array; off1[-1] is valid
// (sentinel zero or previous CSR's last bucket-end) and equals this row-0 start.
__global__ __launch_bounds__(256) void gatherb_kernel(const u16* __restrict__ feat,
                                                      const int* __restrict__ off1,
                                                      const int* __restrict__ pool,
                                                      int n,
                                                      u16* __restrict__ agg) {
    int row = blockIdx.x * 8 + (threadIdx.x >> 5);
    if (row >= n) return;
    int lane = (threadIdx.x & 31) * 4;
    int start = off1[row - 1];
    int end = off1[row];
    float a0[4] = {0.f, 0.f, 0.f, 0.f}, a1[4] = {0.f, 0.f, 0.f, 0.f};
    float a2[4] = {0.f, 0.f, 0.f, 0.f}, a3[4] = {0.f, 0.f, 0.f, 0.f};
    int j = start;
    for (; j + 4 <= end; j += 4) {
        int s0 = pool[j], s1 = pool[j + 1], s2 = pool[j + 2], s3 = pool[j + 3];
        ushort4 v0 = *(const ushort4*)&feat[(i64)s0 * H_ + lane];
        ushort4 v1 = *(const ushort4*)&feat[(i64)s1 * H_ + lane];
        ushort4 v2 = *(const ushort4*)&feat[(i64)s2 * H_ + lane];
        ushort4 v3 = *(const ushort4*)&feat[(i64)s3 * H_ + lane];
        a0[0] += bf2f(v0.x); a0[1] += bf2f(v0.y); a0[2] += bf2f(v0.z); a0[3] += bf2f(v0.w);
        a1[0] += bf2f(v1.x); a1[1] += bf2f(v1.y); a1[2] += bf2f(v1.z); a1[3] += bf2f(v1.w);
        a2[0] += bf2f(v2.x); a2[1] += bf2f(v2.y); a2[2] += bf2f(v2.z); a2[3] += bf2f(v2.w);
        a3[0] += bf2f(v3.x); a3[1] += bf2f(v3.y); a3[2] += bf2f(v3.z); a3[3] += bf2f(v3.w);
    }
    for (; j < end; ++j) {
        int s0 = pool[j];
        ushort4 v0 = *(const ushort4*)&feat[(i64)s0 * H_ + lane];
        a0[0] += bf2f(v0.x); a0[1] += bf2f(v0.y); a0[2] += bf2f(v0.z); a0[3] += bf2f(v0.w);
    }
    float inv = 1.0f / fmaxf((float)(end - start), 1.0f);
    ushort4 o;
    o.x = f2bf((a0[0] + a1[0] + a2[0] + a3[0]) * inv);
    o.y = f2bf((a0[1] + a1[1] + a2[1] + a3[1]) * inv);
    o.z = f2bf((a0[2] + a1[2] + a2[2] + a3[2]) * inv);
    o.w = f2bf((a0[3] + a1[3] + a2[3] + a3[3]) * inv);
    *(ushort4*)&agg[(i64)row * H_ + lane] = o;
}

// ---- weight prep: W (fp32 [K][128], optionally sum of 3) -> frag-tiled hi/lo bf16 ----
// frag layout: index = ((kc*8 + nt)*64 + l)*8 + e  holds  W_T[n=nt*16+(l&15)][k=kc*32+((l>>4)<<3)+e]
struct WJob {
    const float* s0; const float* s1; const float* s2;
    int logK; int base;
};
struct WJobs { WJob j[17]; };

__global__ __launch_bounds__(256) void wsplit_kernel(WJobs jobs, int njobs, int total,
                                                     u16* __restrict__ WTH,
                                                     u16* __restrict__ WTL) {
    int gid = blockIdx.x * 256 + threadIdx.x;
    if (gid >= total) return;
    int ji = 0;
    for (int i = 1; i < 17; ++i)
        if (i < njobs && gid >= jobs.j[i].base) ji = i;
    WJob jb = jobs.j[ji];
    int local = gid - jb.base;
    int e = local & 7;
    int l = (local >> 3) & 63;
    int nt = (local >> 9) & 7;
    int kc = local >> 12;
    int n = nt * 16 + (l & 15);
    int k = kc * 32 + ((l >> 4) << 3) + e;
    i64 si = (i64)k * 128 + n;
    float v = jb.s0[si];
    if (jb.s1 != nullptr) v += jb.s1[si] + jb.s2[si];
    u32 b = __float_as_uint(v);
    u16 h = (u16)(b >> 16);                       // truncation split: v = hi + lo
    float rem = v - __uint_as_float(b & 0xffff0000u);
    WTH[gid] = h;
    WTL[gid] = (u16)(__float_as_uint(rem) >> 16);
}

// ---- x_item GEMM: fp32 A (xif, K=256), 3-term hi/lo split, bf16 output only ----
__device__ __forceinline__ void split8(const float* f, bf16x8& h, bf16x8& lo) {
#pragma unroll
    for (int i = 0; i < 8; ++i) {
        u32 b = __float_as_uint(f[i]);
        h[i] = (short)(u16)(b >> 16);
        float rem = f[i] - __uint_as_float(b & 0xffff0000u);
        lo[i] = (short)(u16)(__float_as_uint(rem) >> 16);
    }
}

__global__ __launch_bounds__(256) void mgemm_x_kernel(
    const float* __restrict__ A, const u16* __restrict__ Wh, const u16* __restrict__ Wl,
    const float* __restrict__ bias, u16* __restrict__ Cbf, int M) {
    int t = threadIdx.x;
    int w = t >> 6, l = t & 63;
    int lr = l & 15, lq = l >> 4;
    int m0 = blockIdx.x * 128 + w * 32;

    f32x4 acc[2][8];
#pragma unroll
    for (int mt = 0; mt < 2; ++mt)
#pragma unroll
        for (int nt = 0; nt < 8; ++nt) acc[mt][nt] = (f32x4){0.f, 0.f, 0.f, 0.f};

    for (int kc = 0; kc < 8; ++kc) {   // K = 256
        bf16x8 ah0, al0, ah1, al1;
        {
            int row = m0 + lr;
            float f[8];
            if (row < M) {
                const float* ap = &A[(i64)row * FEAT_ + kc * 32 + lq * 8];
                *(float4*)&f[0] = *(const float4*)ap;
                *(float4*)&f[4] = *(const float4*)(ap + 4);
            } else {
#pragma unroll
                for (int i = 0; i < 8; ++i) f[i] = 0.f;
            }
            split8(f, ah0, al0);
        }
        {
            int row = m0 + 16 + lr;
            float f[8];
            if (row < M) {
                const float* ap = &A[(i64)row * FEAT_ + kc * 32 + lq * 8];
                *(float4*)&f[0] = *(const float4*)ap;
                *(float4*)&f[4] = *(const float4*)(ap + 4);
            } else {
#pragma unroll
                for (int i = 0; i < 8; ++i) f[i] = 0.f;
            }
            split8(f, ah1, al1);
        }
        const u16* whp = Wh + ((i64)kc * 8) * 512 + (i64)l * 8;
        const u16* wlp = Wl + ((i64)kc * 8) * 512 + (i64)l * 8;
#pragma unroll
        for (int nt = 0; nt < 8; ++nt) {
            bf16x8 bh = *(const bf16x8*)(whp + nt * 512);
            bf16x8 bl = *(const bf16x8*)(wlp + nt * 512);
            acc[0][nt] = __builtin_amdgcn_mfma_f32_16x16x32_bf16(ah0, bh, acc[0][nt], 0, 0, 0);
            acc[1][nt] = __builtin_amdgcn_mfma_f32_16x16x32_bf16(ah1, bh, acc[1][nt], 0, 0, 0);
            acc[0][nt] = __builtin_amdgcn_mfma_f32_16x16x32_bf16(al0, bh, acc[0][nt], 0, 0, 0);
            acc[1][nt] = __builtin_amdgcn_mfma_f32_16x16x32_bf16(al1, bh, acc[1][nt], 0, 0, 0);
            acc[0][nt] = __builtin_amdgcn_mfma_f32_16x16x32_bf16(ah0, bl, acc[0][nt], 0, 0, 0);
            acc[1][nt] = __builtin_amdgcn_mfma_f32_16x16x32_bf16(ah1, bl, acc[1][nt], 0, 0, 0);
        }
    }
#pragma unroll
    for (int nt = 0; nt < 8; ++nt) {
        int col = nt * 16 + lr;
        float bb = bias[col];
#pragma unroll
        for (int mt = 0; mt < 2; ++mt) {
#pragma unroll
            for (int r = 0; r < 4; ++r) {
                int row = m0 + mt * 16 + (lq << 2) + r;
                if (row < M) Cbf[(i64)row * H_ + col] = f2bf(acc[mt][nt][r] + bb);
            }
        }
    }
}

// ---- dual GEMM, bf16 A operands (K=128 each), 2-term W split ----
// out = relu(0.5*(A1@W1 + A2@W2) + 0.5*(b1+b2)); writes fp32 C and/or bf16 Cbf.
__global__ __launch_bounds__(256) void mgemm_d_kernel(
    const u16* __restrict__ A1, const u16* __restrict__ W1h, const u16* __restrict__ W1l,
    const u16* __restrict__ A2, const u16* __restrict__ W2h, const u16* __restrict__ W2l,
    const float* __restrict__ b1, const float* __restrict__ b2,
    float* __restrict__ C, u16* __restrict__ Cbf, int M) {
    int t = threadIdx.x;
    int w = t >> 6, l = t & 63;
    int lr = l & 15, lq = l >> 4;
    int m0 = blockIdx.x * 128 + w * 32;

    f32x4 acc[2][8];
#pragma unroll
    for (int mt = 0; mt < 2; ++mt)
#pragma unroll
        for (int nt = 0; nt < 8; ++nt) acc[mt][nt] = (f32x4){0.f, 0.f, 0.f, 0.f};

#pragma unroll
    for (int mat = 0; mat < 2; ++mat) {
        const u16* A = mat ? A2 : A1;
        const u16* Wh = mat ? W2h : W1h;
        const u16* Wl = mat ? W2l : W1l;
#pragma unroll
        for (int kc = 0; kc < 4; ++kc) {   // K = 128
            bf16x8 a0 = {0, 0, 0, 0, 0, 0, 0, 0}, a1 = {0, 0, 0, 0, 0, 0, 0, 0};
            int row0 = m0 + lr, row1 = m0 + 16 + lr;
            if (row0 < M) a0 = *(const bf16x8*)&A[(i64)row0 * H_ + kc * 32 + lq * 8];
            if (row1 < M) a1 = *(const bf16x8*)&A[(i64)row1 * H_ + kc * 32 + lq * 8];
            const u16* whp = Wh + ((i64)kc * 8) * 512 + (i64)l * 8;
            const u16* wlp = Wl + ((i64)kc * 8) * 512 + (i64)l * 8;
#pragma unroll
            for (int nt = 0; nt < 8; ++nt) {
                bf16x8 bh = *(const bf16x8*)(whp + nt * 512);
                bf16x8 bl = *(const bf16x8*)(wlp + nt * 512);
                acc[0][nt] = __builtin_amdgcn_mfma_f32_16x16x32_bf16(a0, bh, acc[0][nt], 0, 0, 0);
                acc[1][nt] = __builtin_amdgcn_mfma_f32_16x16x32_bf16(a1, bh, acc[1][nt], 0, 0, 0);
                acc[0][nt] = __builtin_amdgcn_mfma_f32_16x16x32_bf16(a0, bl, acc[0][nt], 0, 0, 0);
                acc[1][nt] = __builtin_amdgcn_mfma_f32_16x16x32_bf16(a1, bl, acc[1][nt], 0, 0, 0);
            }
        }
    }
#pragma unroll
    for (int nt = 0; nt < 8; ++nt) {
        int col = nt * 16 + lr;
        float bb = 0.5f * (b1[col] + b2[col]);
#pragma unroll
        for (int mt = 0; mt < 2; ++mt) {
#pragma unroll
            for (int r = 0; r < 4; ++r) {
                int row = m0 + mt * 16 + (lq << 2) + r;
                if (row < M) {
                    float o = fmaxf(0.5f * acc[mt][nt][r] + bb, 0.f);
                    if (C != nullptr) C[(i64)row * H_ + col] = o;
                    if (Cbf != nullptr) Cbf[(i64)row * H_ + col] = f2bf(o);
                }
            }
        }
    }
}

__global__ __launch_bounds__(256) void fuse_kernel(const float* __restrict__ alpha,
                                                   const float* __restrict__ hui,
                                                   const float* __restrict__ hii,
                                                   const float* __restrict__ hia,
                                                   float* __restrict__ fused,
                                                   float* __restrict__ wout) {
    long i = (long)blockIdx.x * 256 + threadIdx.x;
    float a0 = alpha[0], a1 = alpha[1], a2 = alpha[2];
    float mx = fmaxf(a0, fmaxf(a1, a2));
    float e0 = expf(a0 - mx), e1 = expf(a1 - mx), e2 = expf(a2 - mx);
    float inv = 1.f / (e0 + e1 + e2);
    float w0 = e0 * inv, w1 = e1 * inv, w2 = e2 * inv;
    if (i == 0) { wout[0] = w0; wout[1] = w1; wout[2] = w2; }
    long n4 = (long)NI_ * H_ / 4;
    if (i < n4) {
        float4 u = ((const float4*)hui)[i];
        float4 v = ((const float4*)hii)[i];
        float4 t = ((const float4*)hia)[i];
        float4 o;
        o.x = w0 * u.x + w1 * v.x + w2 * t.x;
        o.y = w0 * u.y + w1 * v.y + w2 * t.y;
        o.z = w0 * u.z + w1 * v.z + w2 * t.z;
        o.w = w0 * u.w + w1 * v.w + w2 * t.w;
        ((float4*)fused)[i] = o;
    }
}

extern "C" void kernel_launch(void* const* d_in, const int* in_sizes, int n_in,
                              void* d_out, int out_size, void* d_ws, size_t ws_size,
                              hipStream_t stream) {
    const float* xif  = (const float*)d_in[0];
    const float* uemb = (const float*)d_in[1];
    const float* aemb = (const float*)d_in[2];
    const float* liW  = (const float*)d_in[3];
    const float* lib  = (const float*)d_in[4];
    const float* uiWl = (const float*)d_in[5];
    const float* uibl = (const float*)d_in[6];
    const float* uiWr = (const float*)d_in[7];
    const float* iiWl = (const float*)d_in[8];
    const float* iibl = (const float*)d_in[9];
    const float* iiWr = (const float*)d_in[10];
    const float* iaWl = (const float*)d_in[11];
    const float* iabl = (const float*)d_in[12];
    const float* iaWr = (const float*)d_in[13];
    const float* alpha = (const float*)d_in[14];
    const int* er = (const int*)d_in[15];
    const int* es = (const int*)d_in[16];
    const int* eh = (const int*)d_in[17];

    float* out = (float*)d_out;
    float* FUSED  = out;
    float* OUT_UI = out + (i64)NI_ * H_;
    float* OUT_II = out + (i64)2 * NI_ * H_;
    float* OUT_IA = out + (i64)3 * NI_ * H_;
    float* WOUT   = out + (i64)4 * NI_ * H_;

    // ---- workspace layout: bf16 region first (16B-aligned), then ints ----
    u16* u = (u16*)d_ws;
    i64 uo = 0;
    u16* WTH    = u + uo; uo += 294912;
    u16* WTL    = u + uo; uo += 294912;
    u16* X_bf   = u + uo; uo += (i64)NI_ * H_;
    u16* HI1_bf = u + uo; uo += (i64)NI_ * H_;
    u16* HU1_bf = u + uo; uo += (i64)NU_ * H_;
    u16* HA1_bf = u + uo; uo += (i64)NA_ * H_;
    u16* AGG_bf = u + uo; uo += (i64)NU_ * H_;
    u16* UE_bf  = u + uo; uo += (i64)NU_ * H_;
    u16* AE_bf  = u + uo; uo += (i64)NA_ * H_;

    int* ip = (int*)(u + uo);      // uo even -> 4B aligned; offsets keep 16B
    i64 io = 0;
    int* OFF  = ip + io; io += NTOT_ + 4;   // [0] = sentinel zero; off1 = OFF+1
    int* CNT  = ip + io; io += NTOT_;
    int* POOL = ip + io; io += 2 * ER_ + ES_ + 2 * EH_;   // 3,000,000
    int* BSUM = ip + io; io += 256;
    int* off1 = OFF + 1;

    // ---- CSR build (one fused pass for all 5 graphs) ----
    {
        long nz = NTOT_ + 4 + NTOT_;          // zero OFF (incl sentinel) + CNT
        fillz_kernel<<<(int)((nz / 4 + 255) / 256), 256, 0, stream>>>((float4*)OFF, nz / 4);
        countall_kernel<<<(ETOT_ + 255) / 256, 256, 0, stream>>>(er, es, eh, CNT);
        int nb = (NTOT_ + 1023) / 1024;       // 250
        bsum_kernel<<<nb, 256, 0, stream>>>(CNT, NTOT_, BSUM);
        scan_top_kernel<<<1, 256, 0, stream>>>(BSUM, nb);
        scan_block_kernel<<<nb, 256, 0, stream>>>(CNT, NTOT_, BSUM, off1);
        fillall_kernel<<<(ETOT_ + 255) / 256, 256, 0, stream>>>(er, es, eh, off1, POOL);
    }

    // ---- weight split/transpose ----
    const float* famWl[8] = {uiWl, uiWl, uiWl, iiWl, iiWl, iaWl, iaWl, iaWl};
    const float* famWr[8] = {uiWr, uiWr, uiWr, iiWr, iiWr, iaWr, iaWr, iaWr};
    const float* famBl[8] = {uibl, uibl, uibl, iibl, iibl, iabl, iabl, iabl};
    const int eidx[8] = {0, 1, 4, 0, 2, 0, 1, 5};
    const int sidx[8] = {3, 2, 7, 1, 3, 3, 2, 6};

    WJobs jobs;
    jobs.j[0] = {liW, nullptr, nullptr, 8, 0};
    int base = 32768;
    for (int s = 0; s < 8; ++s) {
        jobs.j[1 + 2 * s] = {famWl[s] + (i64)eidx[s] * 16384, nullptr, nullptr, 7, base};
        base += 16384;
        jobs.j[2 + 2 * s] = {famWr[s] + (i64)eidx[s] * 16384,
                             famWl[s] + (i64)sidx[s] * 16384,
                             famWr[s] + (i64)sidx[s] * 16384, 7, base};
        base += 16384;
    }
    wsplit_kernel<<<(base + 255) / 256, 256, 0, stream>>>(jobs, 17, base, WTH, WTL);

    // ---- bf16 copies of input embedding tables ----
    tobf_kernel<<<((NU_ * H_ / 4) + 255) / 256, 256, 0, stream>>>(
        (const float4*)uemb, (ushort4*)UE_bf, (long)NU_ * H_ / 4);
    tobf_kernel<<<((NA_ * H_ / 4) + 255) / 256, 256, 0, stream>>>(
        (const float4*)aemb, (ushort4*)AE_bf, (long)NA_ * H_ / 4);

    // x_item = xif @ liW + lib  -> bf16 table
    mgemm_x_kernel<<<(NI_ + 127) / 128, 256, 0, stream>>>(xif, WTH, WTL, lib, X_bf, NI_);

    auto gath = [&](const u16* feat, int cbase, int ndst) {
        gatherb_kernel<<<(ndst + 7) / 8, 256, 0, stream>>>(feat, off1 + cbase, POOL, ndst, AGG_bf);
    };
    auto gemm2 = [&](int slot, const u16* A2m, float* Cout, u16* Cbfout, int M) {
        const u16* w1h = WTH + 32768 + (i64)(2 * slot) * 16384;
        const u16* w1l = WTL + 32768 + (i64)(2 * slot) * 16384;
        const u16* w2h = WTH + 32768 + (i64)(2 * slot + 1) * 16384;
        const u16* w2l = WTL + 32768 + (i64)(2 * slot + 1) * 16384;
        const float* be = famBl[slot] + (i64)eidx[slot] * 128;
        const float* bs = famBl[slot] + (i64)sidx[slot] * 128;
        mgemm_d_kernel<<<(M + 127) / 128, 256, 0, stream>>>(
            AGG_bf, w1h, w1l, A2m, w2h, w2l, be, bs, Cout, Cbfout, M);
    };

    // ---- UI branch ----
    gath(UE_bf, B_RI, NI_);
    gemm2(0, X_bf, nullptr, HI1_bf, NI_);
    gath(X_bf, B_RU, NU_);
    gemm2(1, UE_bf, nullptr, HU1_bf, NU_);
    gath(HU1_bf, B_RI, NI_);                 // L1 o_i only (o_u dead)
    gemm2(2, HI1_bf, OUT_UI, nullptr, NI_);

    // ---- II branch ----
    gath(X_bf, B_SI, NI_);
    gemm2(3, X_bf, nullptr, HI1_bf, NI_);
    gath(HI1_bf, B_SI, NI_);
    gemm2(4, HI1_bf, OUT_II, nullptr, NI_);

    // ---- IA branch ----
    gath(X_bf, B_HA, NA_);
    gemm2(5, AE_bf, nullptr, HA1_bf, NA_);
    gath(AE_bf, B_HI, NI_);
    gemm2(6, X_bf, nullptr, HI1_bf, NI_);
    gath(HA1_bf, B_HI, NI_);                 // L1 o_i only (o_a dead)
    gemm2(7, HI1_bf, OUT_IA, nullptr, NI_);

    // ---- fuse ----
    long n4 = (long)NI_ * H_ / 4;
    fuse_kernel<<<(int)((n4 + 255) / 256), 256, 0, stream>>>(
        alpha, OUT_UI, OUT_II, OUT_IA, FUSED, WOUT);
}